// Round 6
// baseline (4317.975 us; speedup 1.0000x reference)
//
#include <hip/hip_runtime.h>

typedef unsigned int uint;
typedef unsigned short u16;

#define BB 4
#define CE 384
#define DD 512
#define LL 8
#define HH 16
#define MM 2048
#define NJ 163
#define TOK 4096
#define BKQ 64
#define QH 256
#define OUTW 1486
#define NROT 978
#define NBLK 256

typedef __attribute__((ext_vector_type(8))) short short8;
typedef __attribute__((ext_vector_type(4))) float float4v;

static __device__ __forceinline__ u16 f2bf(float f){
  union { float f; uint u; } c; c.f = f;
  uint u = c.u;
  return (u16)((u + 0x7FFFu + ((u >> 16) & 1u)) >> 16);
}
static __device__ __forceinline__ float wred_sum(float v){
  for (int o = 32; o; o >>= 1) v += __shfl_xor(v, o, 64);
  return v;
}
static __device__ __forceinline__ void gl16(const void* g, void* l){
  __builtin_amdgcn_global_load_lds((const __attribute__((address_space(1))) void*)g,
                                   (__attribute__((address_space(3))) void*)l, 16, 0, 0);
}
// monotonic grid barrier (all NBLK blocks co-resident)
static __device__ __forceinline__ void gbar(int* cnt, int& bars){
  bars++;
  __syncthreads();
  if (threadIdx.x == 0){
    __threadfence();
    __hip_atomic_fetch_add(cnt, 1, __ATOMIC_ACQ_REL, __HIP_MEMORY_SCOPE_AGENT);
    while (__hip_atomic_load(cnt, __ATOMIC_ACQUIRE, __HIP_MEMORY_SCOPE_AGENT) < bars*NBLK)
      __builtin_amdgcn_s_sleep(8);
  }
  __syncthreads();
  __threadfence();
}

// ---------------- NMS + top-k (register scan, exact fp32, stable ties) ----------------
__global__ __launch_bounds__(256) void k_nms_topk(const float* __restrict__ scores,
    int* __restrict__ oidx, float* __restrict__ omask, float* __restrict__ ocol, float* __restrict__ orow)
{
  int b = blockIdx.x, t = threadIdx.x;
  __shared__ float sraw[4096];
  __shared__ float sv[4]; __shared__ int si[4]; __shared__ int swin;
  const float* sp = scores + (size_t)b * 4096;
  for (int i = t; i < 4096; i += 256) sraw[i] = sp[i];
  __syncthreads();
  float v[16];
  #pragma unroll
  for (int j = 0; j < 16; j++){
    int i = t + j*256;
    int r = i >> 6, c = i & 63;
    float mx = -1e30f;
    for (int dr = -1; dr <= 1; dr++){
      int rr = r + dr; if (rr < 0 || rr > 63) continue;
      for (int dc = -1; dc <= 1; dc++){
        int cc = c + dc; if (cc < 0 || cc > 63) continue;
        mx = fmaxf(mx, sraw[rr*64+cc]);
      }
    }
    float s = sraw[i];
    v[j] = (s == mx) ? s : 0.0f;
  }
  int lane = t & 63, wv = t >> 6;
  for (int iter = 0; iter < 16; iter++){
    float best = -1e30f; int bi_ = 1 << 30;
    #pragma unroll
    for (int j = 0; j < 16; j++){
      if (v[j] > best){ best = v[j]; bi_ = t + j*256; }
    }
    #pragma unroll
    for (int o = 32; o; o >>= 1){
      float ov = __shfl_xor(best, o, 64);
      int oi = __shfl_xor(bi_, o, 64);
      if (ov > best || (ov == best && oi < bi_)){ best = ov; bi_ = oi; }
    }
    if (lane == 0){ sv[wv] = best; si[wv] = bi_; }
    __syncthreads();
    if (t == 0){
      float bb = sv[0]; int ii = si[0];
      for (int k = 1; k < 4; k++){
        if (sv[k] > bb || (sv[k] == bb && si[k] < ii)){ bb = sv[k]; ii = si[k]; }
      }
      oidx[b*16+iter] = ii;
      omask[b*16+iter] = (bb >= 0.3f) ? 1.f : 0.f;
      ocol[b*16+iter] = (float)(ii & 63);
      orow[b*16+iter] = (float)(ii >> 6);
      swin = ii;
    }
    __syncthreads();
    int wi = swin;
    if ((wi & 255) == t) v[wi >> 8] = -1e30f;
    __syncthreads();
  }
}

// ---------------- fp32 -> bf16 convert ----------------
__global__ __launch_bounds__(256) void k_cvt_bf16(const float* __restrict__ in, u16* __restrict__ out, int n4){
  int i = blockIdx.x*256 + threadIdx.x;
  int stride = gridDim.x*256;
  for (int j = i; j < n4; j += stride){
    float4 v = ((const float4*)in)[j];
    ushort4 o;
    o.x = f2bf(v.x); o.y = f2bf(v.y); o.z = f2bf(v.z); o.w = f2bf(v.w);
    ((ushort4*)out)[j] = o;
  }
}

// ---------------- unified transpose+convert: up to 24 jobs fp32(R,C)->bf16(C,R) ----------------
struct PJobs {
  const float* s[24]; u16* d[24];
  int R[24], C[24], t0[25];
  int njobs, ntiles;
};
__global__ __launch_bounds__(256) void k_prepw(PJobs J){
  __shared__ float tile[32][33];
  for (int g = blockIdx.x; g < J.ntiles; g += gridDim.x){
    int j = 0;
    while (g >= J.t0[j+1]) j++;
    int ti = g - J.t0[j];
    int C_ = J.C[j], R_ = J.R[j];
    int tC = (C_ + 31) >> 5;
    int ry = ti / tC, cx = ti - ry*tC;
    int c0 = cx*32, r0 = ry*32;
    int tx = threadIdx.x & 31, ty = threadIdx.x >> 5;
    const float* src = J.s[j]; u16* dst = J.d[j];
    for (int i = 0; i < 32; i += 8){
      float v = 0.f;
      if (c0+tx < C_) v = src[(size_t)(r0+ty+i)*C_ + c0+tx];
      tile[ty+i][tx] = v;
    }
    __syncthreads();
    for (int i = 0; i < 32; i += 8){
      if (c0+ty+i < C_) dst[(size_t)(c0+ty+i)*R_ + r0+tx] = f2bf(tile[tx][ty+i]);
    }
    __syncthreads();
  }
}

// ---------------- bf16 transpose (R,C) -> (C,R), batched in z ----------------
__global__ __launch_bounds__(256) void k_transp_b(const u16* __restrict__ in, u16* __restrict__ out, int R, int C){
  in  += (size_t)blockIdx.z * R * C;
  out += (size_t)blockIdx.z * R * C;
  __shared__ u16 tile[32][33];
  int c0 = blockIdx.x*32, r0 = blockIdx.y*32;
  int tx = threadIdx.x & 31, ty = threadIdx.x >> 5;
  for (int i = 0; i < 32; i += 8) tile[ty+i][tx] = in[(size_t)(r0+ty+i)*C + c0+tx];
  __syncthreads();
  for (int i = 0; i < 32; i += 8) out[(size_t)(c0+ty+i)*R + r0+tx] = tile[tx][ty+i];
}

// ---------------- ctx embed GEMM: ctx = feat_bf @ wtokT^T + btok + pos_emb -> bf16 ----------------
__global__ __launch_bounds__(256) void k_gemm_emb(
    const u16* __restrict__ A, const u16* __restrict__ Bt, u16* __restrict__ Cb,
    const float* __restrict__ ep1, const float* __restrict__ ep2)
{
  int m0 = blockIdx.y*128, n0 = blockIdx.x*128;
  __shared__ __align__(16) u16 As[128*64];
  __shared__ __align__(16) u16 Bs[128*64];
  int t = threadIdx.x, lane = t & 63, wave = t >> 6;
  int wr = wave >> 1, wc = wave & 1;
  int lr = lane & 15, lk = lane >> 4;
  int sr8 = t >> 3, sl = t & 7;
  int sw = ((sl ^ (sr8 & 7)) * 8);
  float4v acc[4][4];
  float4v z4 = {0.f, 0.f, 0.f, 0.f};
  #pragma unroll
  for (int i = 0; i < 4; i++)
    #pragma unroll
    for (int j = 0; j < 4; j++) acc[i][j] = z4;
  for (int kt = 0; kt < CE; kt += 64){
    __syncthreads();
    #pragma unroll
    for (int rg = 0; rg < 4; rg++){
      gl16(A + (size_t)(m0 + rg*32 + sr8)*CE + kt + sw, As + rg*2048 + 8*t);
      gl16(Bt + (size_t)(n0 + rg*32 + sr8)*CE + kt + sw, Bs + rg*2048 + 8*t);
    }
    __syncthreads();
    #pragma unroll
    for (int s = 0; s < 2; s++){
      int slot = ((s*4 + lk) ^ (lr & 7)) * 8;
      short8 af[4], bfr[4];
      #pragma unroll
      for (int i = 0; i < 4; i++) af[i] = *(const short8*)&As[(wr*64 + i*16 + lr)*64 + slot];
      #pragma unroll
      for (int j = 0; j < 4; j++) bfr[j] = *(const short8*)&Bs[(wc*64 + j*16 + lr)*64 + slot];
      #pragma unroll
      for (int i = 0; i < 4; i++)
        #pragma unroll
        for (int j = 0; j < 4; j++)
          acc[i][j] = __builtin_amdgcn_mfma_f32_16x16x32_bf16(af[i], bfr[j], acc[i][j], 0, 0, 0);
    }
  }
  #pragma unroll
  for (int i = 0; i < 4; i++){
    int rbase = m0 + wr*64 + i*16 + lk*4;
    #pragma unroll
    for (int j = 0; j < 4; j++){
      int cc = n0 + wc*64 + j*16 + lr;
      #pragma unroll
      for (int jj = 0; jj < 4; jj++){
        int rr = rbase + jj;
        float vv = acc[i][j][jj] + ep1[cc] + ep2[(size_t)(rr & 4095)*DD + cc];
        Cb[(size_t)rr*DD + cc] = f2bf(vv);
      }
    }
  }
}

// ---------------- misc: gather + pose-const + bias packing ----------------
__global__ __launch_bounds__(256) void k_misc(const float* __restrict__ feat, const float* __restrict__ Wtok,
    const float* __restrict__ btok, const float* __restrict__ pos_emb, const int* __restrict__ oidx,
    float* __restrict__ x, const float* __restrict__ pW1, const float* __restrict__ pb1,
    const float* __restrict__ ibp, float* __restrict__ hb4,
    const float* __restrict__ offb1, const float* __restrict__ db1, const float* __restrict__ sb1,
    const float* __restrict__ pb2, float* __restrict__ cvec2)
{
  int bid = blockIdx.x, t = threadIdx.x;
  if (bid < 64){
    int b = bid >> 4, tok = oidx[bid];
    __shared__ float fs[CE];
    const float* fr = feat + ((size_t)b*TOK + tok) * CE;
    for (int i = t; i < CE; i += 256) fs[i] = fr[i];
    __syncthreads();
    for (int d = t; d < DD; d += 256){
      float acc = btok[d] + pos_emb[(size_t)tok*DD + d];
      for (int i = 0; i < CE; i++) acc += fs[i] * Wtok[(size_t)i*DD + d];
      x[(size_t)bid*DD + d] = acc;
    }
  } else if (bid < 192){
    int d = (bid - 64)*4 + (t >> 6);
    int ln = t & 63;
    float acc = 0.f;
    for (int i = ln; i < NJ*6; i += 64) acc += ibp[i] * pW1[(size_t)(DD+i)*DD + d];
    acc = wred_sum(acc);
    if (ln == 0) hb4[1536 + d] = acc + pb1[d];
  } else {
    for (int i = t; i < 1536; i += 256)
      hb4[i] = (i < 512) ? offb1[i] : (i < 1024 ? db1[i-512] : sb1[i-1024]);
    for (int i = t; i < 1024; i += 256)
      cvec2[i] = (i < NJ*6) ? (pb2[i] + ibp[i]) : 0.f;
  }
}

// ================= mega kernel =================
struct MG {
  float* x; u16* z; const u16* ctx; const u16* ctxT;
  float* logits; u16* att; u16* mid;
  u16* AT; u16* WVO;
  const u16* w1T; const u16* w2T;
  const float* Wq; const float* Wk; const float* Wv; const float* Wo;
  const float* g1; const float* b1n; const float* g2; const float* b2n;
  const float* bf1; const float* bf2;
  const u16* headsT; const float* hb4; const u16* pw2T; const float* cvec2;
  float* h4; u16* hp; float* rot6d;
  const float* offW2; const float* offb2; const float* dW2; const float* db2;
  const float* sW2; const float* sb2; const float* K_cam; const float* useful;
  const float* maskf; const float* colf; const float* rowf; float* out;
  int* bar;
};

#define QKSCALE 0.17677669529663687f

// LayerNorm 64 rows of x -> bf16 LDS tile [64][520]
static __device__ __forceinline__ void d_lnlds(const float* __restrict__ xb,
    const float* __restrict__ g, const float* __restrict__ bb, u16* A, int t)
{
  int rg = t >> 4, lc = t & 15;
  for (int r0 = 0; r0 < 64; r0 += 16){
    int row = r0 + rg;
    const float* xr = xb + (size_t)row*DD + lc*32;
    float4 va[8]; float s = 0.f;
    #pragma unroll
    for (int j = 0; j < 8; j++){ va[j] = *(const float4*)(xr + j*4); s += va[j].x+va[j].y+va[j].z+va[j].w; }
    #pragma unroll
    for (int o = 8; o; o >>= 1) s += __shfl_xor(s, o, 64);
    float mu = s * (1.f/DD);
    float q = 0.f;
    #pragma unroll
    for (int j = 0; j < 8; j++){
      va[j].x -= mu; va[j].y -= mu; va[j].z -= mu; va[j].w -= mu;
      q += va[j].x*va[j].x + va[j].y*va[j].y + va[j].z*va[j].z + va[j].w*va[j].w;
    }
    #pragma unroll
    for (int o = 8; o; o >>= 1) q += __shfl_xor(q, o, 64);
    float inv = rsqrtf(q * (1.f/DD) + 1e-5f);
    u16* dst = A + row*520 + lc*32;
    #pragma unroll
    for (int j = 0; j < 8; j++){
      float4 gg = *(const float4*)(g + lc*32 + j*4);
      float4 bv = *(const float4*)(bb + lc*32 + j*4);
      dst[j*4+0] = f2bf(va[j].x*inv*gg.x + bv.x);
      dst[j*4+1] = f2bf(va[j].y*inv*gg.y + bv.y);
      dst[j*4+2] = f2bf(va[j].z*inv*gg.z + bv.z);
      dst[j*4+3] = f2bf(va[j].w*inv*gg.w + bv.w);
    }
  }
}

// stage 64 rows x 64 cols of Bt into Bs (gl16, XOR-swizzled both sides)
// NOTE: second half of the tile (rows 32..63) lives at +2048 u16 (32 rows x 64 u16)
static __device__ __forceinline__ void d_stageB64(const u16* __restrict__ Bt, int n0, int kt, int ldb, u16* Bs, int t){
  int sr8 = t >> 3, sl = t & 7;
  int sw = ((sl ^ (sr8 & 7)) * 8);
  gl16(Bt + (size_t)(n0 + sr8)*ldb + kt + sw, Bs + 8*t);
  gl16(Bt + (size_t)(n0 + 32 + sr8)*ldb + kt + sw, Bs + 2048 + 8*t);
}

// 128x128 MFMA GEMM tile, gl16-staged
static __device__ __forceinline__ void d_gemm128(const u16* __restrict__ Ab, const u16* __restrict__ Bb,
    float* __restrict__ C, int m0, int n0, int kbeg, int kcnt,
    int lda, int ldb, int ldc, u16* As, u16* Bs, int t)
{
  int lane = t & 63, wave = t >> 6;
  int wr = wave >> 1, wc = wave & 1;
  int lr = lane & 15, lk = lane >> 4;
  int sr8 = t >> 3, sl = t & 7;
  int sw = ((sl ^ (sr8 & 7)) * 8);
  float4v acc[4][4];
  float4v z4 = {0.f,0.f,0.f,0.f};
  #pragma unroll
  for (int i = 0; i < 4; i++)
    #pragma unroll
    for (int j = 0; j < 4; j++) acc[i][j] = z4;
  for (int kt = kbeg; kt < kbeg + kcnt; kt += 64){
    __syncthreads();
    #pragma unroll
    for (int rg = 0; rg < 4; rg++){
      gl16(Ab + (size_t)(m0 + rg*32 + sr8)*lda + kt + sw, As + rg*2048 + 8*t);
      gl16(Bb + (size_t)(n0 + rg*32 + sr8)*ldb + kt + sw, Bs + rg*2048 + 8*t);
    }
    __syncthreads();
    #pragma unroll
    for (int s = 0; s < 2; s++){
      int slot = ((s*4 + lk) ^ (lr & 7)) * 8;
      short8 af[4], bfr[4];
      #pragma unroll
      for (int i = 0; i < 4; i++) af[i] = *(const short8*)&As[(wr*64 + i*16 + lr)*64 + slot];
      #pragma unroll
      for (int j = 0; j < 4; j++) bfr[j] = *(const short8*)&Bs[(wc*64 + j*16 + lr)*64 + slot];
      #pragma unroll
      for (int i = 0; i < 4; i++)
        #pragma unroll
        for (int j = 0; j < 4; j++)
          acc[i][j] = __builtin_amdgcn_mfma_f32_16x16x32_bf16(af[i], bfr[j], acc[i][j], 0, 0, 0);
    }
  }
  #pragma unroll
  for (int i = 0; i < 4; i++){
    #pragma unroll
    for (int j = 0; j < 4; j++){
      int cc = n0 + wc*64 + j*16 + lr;
      #pragma unroll
      for (int jj = 0; jj < 4; jj++){
        int rr = m0 + wr*64 + i*16 + lk*4 + jj;
        C[(size_t)rr*ldc + cc] = acc[i][j][jj];
      }
    }
  }
}

// AT tile: AT[(h*512+dout)][din] = QKSCALE * sum_dh Wq[din][h*32+dh]*Wk[dout][h*32+dh]
static __device__ __forceinline__ void d_wqk(int l, int id, const float* __restrict__ Wq,
    const float* __restrict__ Wk, u16* __restrict__ AT, u16* As, u16* Bs, int t)
{
  int rt = id & 127, dt = id >> 7;
  int h = rt >> 3, dout0 = (rt & 7)*64, din0 = dt*64;
  const float* wq = Wq + (size_t)l*DD*DD;
  const float* wk = Wk + (size_t)l*DD*DD;
  int r = t >> 2, c0 = (t & 3)*8;
  {
    float4 u0 = *(const float4*)(wk + (size_t)(dout0+r)*DD + h*32 + c0);
    float4 u1 = *(const float4*)(wk + (size_t)(dout0+r)*DD + h*32 + c0 + 4);
    u16* d = As + r*40 + c0;
    d[0]=f2bf(u0.x); d[1]=f2bf(u0.y); d[2]=f2bf(u0.z); d[3]=f2bf(u0.w);
    d[4]=f2bf(u1.x); d[5]=f2bf(u1.y); d[6]=f2bf(u1.z); d[7]=f2bf(u1.w);
    float4 v0 = *(const float4*)(wq + (size_t)(din0+r)*DD + h*32 + c0);
    float4 v1 = *(const float4*)(wq + (size_t)(din0+r)*DD + h*32 + c0 + 4);
    u16* e = Bs + r*40 + c0;
    e[0]=f2bf(v0.x); e[1]=f2bf(v0.y); e[2]=f2bf(v0.z); e[3]=f2bf(v0.w);
    e[4]=f2bf(v1.x); e[5]=f2bf(v1.y); e[6]=f2bf(v1.z); e[7]=f2bf(v1.w);
  }
  __syncthreads();
  int lane = t & 63, w = t >> 6, lr = lane & 15, lk = lane >> 4;
  short8 af = *(const short8*)&As[(w*16+lr)*40 + lk*8];
  float4v acc[4];
  float4v z4 = {0.f,0.f,0.f,0.f};
  acc[0]=z4; acc[1]=z4; acc[2]=z4; acc[3]=z4;
  #pragma unroll
  for (int nf = 0; nf < 4; nf++){
    short8 bf8 = *(const short8*)&Bs[(nf*16+lr)*40 + lk*8];
    acc[nf] = __builtin_amdgcn_mfma_f32_16x16x32_bf16(af, bf8, acc[nf], 0, 0, 0);
  }
  #pragma unroll
  for (int nf = 0; nf < 4; nf++){
    #pragma unroll
    for (int jj = 0; jj < 4; jj++){
      int row = w*16 + lk*4 + jj;
      AT[(size_t)(h*512 + dout0 + row)*DD + din0 + nf*16 + lr] = f2bf(acc[nf][jj]*QKSCALE);
    }
  }
  __syncthreads();
}

// WVO tile: WVOT[dout][(h*512+Dc)] = sum_c Wv[Dc][h*32+c]*Wo[h*32+c][dout]
static __device__ __forceinline__ void d_wvo(int l, int id, const float* __restrict__ Wv,
    const float* __restrict__ Wo, u16* __restrict__ WVOT, u16* As, u16* Bs, int t)
{
  int ct = id & 127, dt = id >> 7;
  int h = ct >> 3, Dc0 = (ct & 7)*64, dout0 = dt*64;
  const float* wv = Wv + (size_t)l*DD*DD;
  const float* wo = Wo + (size_t)l*DD*DD;
  {
    int c = t >> 3, d8 = (t & 7)*8;
    float4 a0 = *(const float4*)(wo + (size_t)(h*32+c)*DD + dout0 + d8);
    float4 a1 = *(const float4*)(wo + (size_t)(h*32+c)*DD + dout0 + d8 + 4);
    As[(d8+0)*40 + c] = f2bf(a0.x);
    As[(d8+1)*40 + c] = f2bf(a0.y);
    As[(d8+2)*40 + c] = f2bf(a0.z);
    As[(d8+3)*40 + c] = f2bf(a0.w);
    As[(d8+4)*40 + c] = f2bf(a1.x);
    As[(d8+5)*40 + c] = f2bf(a1.y);
    As[(d8+6)*40 + c] = f2bf(a1.z);
    As[(d8+7)*40 + c] = f2bf(a1.w);
    int r = t >> 2, c0 = (t & 3)*8;
    float4 v0 = *(const float4*)(wv + (size_t)(Dc0+r)*DD + h*32 + c0);
    float4 v1 = *(const float4*)(wv + (size_t)(Dc0+r)*DD + h*32 + c0 + 4);
    u16* e = Bs + r*40 + c0;
    e[0]=f2bf(v0.x); e[1]=f2bf(v0.y); e[2]=f2bf(v0.z); e[3]=f2bf(v0.w);
    e[4]=f2bf(v1.x); e[5]=f2bf(v1.y); e[6]=f2bf(v1.z); e[7]=f2bf(v1.w);
  }
  __syncthreads();
  int lane = t & 63, w = t >> 6, lr = lane & 15, lk = lane >> 4;
  short8 af = *(const short8*)&As[(w*16+lr)*40 + lk*8];
  float4v acc[4];
  float4v z4 = {0.f,0.f,0.f,0.f};
  acc[0]=z4; acc[1]=z4; acc[2]=z4; acc[3]=z4;
  #pragma unroll
  for (int nf = 0; nf < 4; nf++){
    short8 bf8 = *(const short8*)&Bs[(nf*16+lr)*40 + lk*8];
    acc[nf] = __builtin_amdgcn_mfma_f32_16x16x32_bf16(af, bf8, acc[nf], 0, 0, 0);
  }
  #pragma unroll
  for (int nf = 0; nf < 4; nf++){
    #pragma unroll
    for (int jj = 0; jj < 4; jj++){
      int row = w*16 + lk*4 + jj;
      WVOT[(size_t)(dout0 + row)*8192 + h*512 + Dc0 + nf*16 + lr] = f2bf(acc[nf][jj]);
    }
  }
  __syncthreads();
}

__global__ __launch_bounds__(256) void k_layers(MG A){
  __shared__ __align__(16) u16 SM[37632];
  __shared__ float SF[96];
  int bid = blockIdx.x, t = threadIdx.x;
  int bars = 0;
  u16* AslLN = SM;              // 64*520
  u16* Bs64  = SM + 33280;      // 64*64
  u16* As128 = SM;              // 128*64
  u16* Bs128 = SM + 8192;       // 128*64
  int lane = t & 63, w = t >> 6, lr = lane & 15, lk = lane >> 4;
  float4v z4 = {0.f,0.f,0.f,0.f};

  // prologue: AT_0 + WVO_0
  for (int j = 0; j < 8; j++){
    int id = bid + j*256;
    if (id < 1024) d_wqk(0, id, A.Wq, A.Wk, A.AT, SM, SM + 4096, t);
    else d_wvo(0, id - 1024, A.Wv, A.Wo, A.WVO, SM, SM + 4096, t);
  }
  gbar(A.bar, bars);

  for (int l = 0; l < LL; l++){
    // ---- P0: Z = LN1(x) @ AT^T (128 blocks) ----
    if (bid < 128){
      d_lnlds(A.x, A.g1 + l*DD, A.b1n + l*DD, AslLN, t);
      int n0 = bid*64;
      float4v acc[4]; acc[0]=z4; acc[1]=z4; acc[2]=z4; acc[3]=z4;
      for (int kc = 0; kc < 512; kc += 64){
        __syncthreads();
        d_stageB64(A.AT, n0, kc, 512, Bs64, t);
        __syncthreads();
        #pragma unroll
        for (int s = 0; s < 2; s++){
          int slot = ((s*4 + lk) ^ (lr & 7)) * 8;
          short8 af = *(const short8*)&AslLN[(w*16+lr)*520 + kc + s*32 + lk*8];
          #pragma unroll
          for (int nf = 0; nf < 4; nf++){
            short8 bf8 = *(const short8*)&Bs64[(nf*16+lr)*64 + slot];
            acc[nf] = __builtin_amdgcn_mfma_f32_16x16x32_bf16(af, bf8, acc[nf], 0, 0, 0);
          }
        }
      }
      #pragma unroll
      for (int nf = 0; nf < 4; nf++)
        #pragma unroll
        for (int jj = 0; jj < 4; jj++)
          A.z[(size_t)(w*16 + lk*4 + jj)*8192 + n0 + nf*16 + lr] = f2bf(acc[nf][jj]);
    }
    gbar(A.bar, bars);

    // ---- P1: logits (256 blocks) ----
    {
      int nt = bid & 31, mt = (bid >> 5) & 1, b = bid >> 6;
      d_gemm128(A.z + (size_t)b*131072, A.ctx + (size_t)b*TOK*DD,
                A.logits + (size_t)b*QH*TOK,
                mt*128, nt*128, 0, 512, 512, 512, TOK, As128, Bs128, t);
    }
    gbar(A.bar, bars);

    // ---- P2: softmax 4 rows/block -> att bf16 ----
    for (int rr4 = 0; rr4 < 4; rr4++){
      int row = bid*4 + rr4;
      const float* p = A.logits + (size_t)row*TOK;
      float vv[16]; float mx = -1e30f;
      #pragma unroll
      for (int i = 0; i < 16; i++){ vv[i] = p[t + i*256]; mx = fmaxf(mx, vv[i]); }
      for (int o = 32; o; o >>= 1) mx = fmaxf(mx, __shfl_xor(mx, o, 64));
      if (lane == 0) SF[w] = mx;
      __syncthreads();
      mx = fmaxf(fmaxf(SF[0], SF[1]), fmaxf(SF[2], SF[3]));
      float s = 0.f;
      #pragma unroll
      for (int i = 0; i < 16; i++){ vv[i] = expf(vv[i] - mx); s += vv[i]; }
      s = wred_sum(s);
      if (lane == 0) SF[4+w] = s;
      __syncthreads();
      s = SF[4]+SF[5]+SF[6]+SF[7];
      float inv = 1.f / s;
      u16* q = A.att + (size_t)row*TOK;
      #pragma unroll
      for (int i = 0; i < 16; i++) q[t + i*256] = f2bf(vv[i]*inv);
      __syncthreads();
    }
    gbar(A.bar, bars);

    // ---- P3: PV partials ksplit4 (128 blocks) + AT_{l+1} prep (128 blocks) ----
    if (bid < 128){
      int nt = bid & 3, mt = (bid >> 2) & 1, b = (bid >> 3) & 3, ks = bid >> 5;
      float* part = A.logits;  // logits dead; partials [b*4+ks][256][512]
      d_gemm128(A.att + (size_t)b*QH*TOK, A.ctxT + (size_t)b*DD*TOK,
                part + (size_t)(b*4 + ks)*QH*DD,
                mt*128, nt*128, ks*1024, 1024, TOK, TOK, DD, As128, Bs128, t);
    } else if (l < LL-1){
      int base = bid - 128;
      for (int j = 0; j < 8; j++) d_wqk(l+1, base + j*128, A.Wq, A.Wk, A.AT, SM, SM + 4096, t);
    }
    gbar(A.bar, bars);

    // ---- P4: x += (sum_s partials) @ WVO^T (128 blocks) ----
    if (bid < 128){
      int n0 = (bid & 7)*64, ks = bid >> 3;   // ks 0..15 over K=8192
      const float* part = A.logits;
      float4v acc[4]; acc[0]=z4; acc[1]=z4; acc[2]=z4; acc[3]=z4;
      int kbeg = ks*512;
      for (int kc = kbeg; kc < kbeg + 512; kc += 64){
        __syncthreads();
        {
          int rr = t >> 2, c0 = (t & 3)*16;
          int b = rr >> 4, q = rr & 15;
          const float* pb = part + (size_t)b*524288 + (size_t)q*8192 + kc + c0;
          float4 f0 = *(const float4*)(pb);
          float4 f1 = *(const float4*)(pb + 4);
          float4 f2 = *(const float4*)(pb + 8);
          float4 f3 = *(const float4*)(pb + 12);
          #pragma unroll
          for (int s2 = 1; s2 < 4; s2++){
            const float* ps = pb + (size_t)s2*131072;
            float4 g0 = *(const float4*)(ps);
            float4 g1 = *(const float4*)(ps + 4);
            float4 g2 = *(const float4*)(ps + 8);
            float4 g3 = *(const float4*)(ps + 12);
            f0.x+=g0.x; f0.y+=g0.y; f0.z+=g0.z; f0.w+=g0.w;
            f1.x+=g1.x; f1.y+=g1.y; f1.z+=g1.z; f1.w+=g1.w;
            f2.x+=g2.x; f2.y+=g2.y; f2.z+=g2.z; f2.w+=g2.w;
            f3.x+=g3.x; f3.y+=g3.y; f3.z+=g3.z; f3.w+=g3.w;
          }
          u16* d = SM + rr*72 + c0;
          d[0]=f2bf(f0.x); d[1]=f2bf(f0.y); d[2]=f2bf(f0.z); d[3]=f2bf(f0.w);
          d[4]=f2bf(f1.x); d[5]=f2bf(f1.y); d[6]=f2bf(f1.z); d[7]=f2bf(f1.w);
          d[8]=f2bf(f2.x); d[9]=f2bf(f2.y); d[10]=f2bf(f2.z); d[11]=f2bf(f2.w);
          d[12]=f2bf(f3.x); d[13]=f2bf(f3.y); d[14]=f2bf(f3.z); d[15]=f2bf(f3.w);
        }
        d_stageB64(A.WVO, n0, kc, 8192, Bs64, t);
        __syncthreads();
        #pragma unroll
        for (int s = 0; s < 2; s++){
          int slot = ((s*4 + lk) ^ (lr & 7)) * 8;
          short8 af = *(const short8*)&SM[(w*16+lr)*72 + s*32 + lk*8];
          #pragma unroll
          for (int nf = 0; nf < 4; nf++){
            short8 bf8 = *(const short8*)&Bs64[(nf*16+lr)*64 + slot];
            acc[nf] = __builtin_amdgcn_mfma_f32_16x16x32_bf16(af, bf8, acc[nf], 0, 0, 0);
          }
        }
      }
      #pragma unroll
      for (int nf = 0; nf < 4; nf++)
        #pragma unroll
        for (int jj = 0; jj < 4; jj++)
          atomicAdd(&A.x[(size_t)(w*16 + lk*4 + jj)*DD + n0 + nf*16 + lr], acc[nf][jj]);
    }
    gbar(A.bar, bars);

    // ---- P5: mid = gelu(LN2(x) @ W1 + bf1) (32 blocks) + WVO_{l+1} prep (224 blocks) ----
    if (bid < 32){
      d_lnlds(A.x, A.g2 + l*DD, A.b2n + l*DD, AslLN, t);
      int n0 = bid*64;
      const u16* Bt = A.w1T + (size_t)l*MM*DD;
      float4v acc[4]; acc[0]=z4; acc[1]=z4; acc[2]=z4; acc[3]=z4;
      for (int kc = 0; kc < 512; kc += 64){
        __syncthreads();
        d_stageB64(Bt, n0, kc, 512, Bs64, t);
        __syncthreads();
        #pragma unroll
        for (int s = 0; s < 2; s++){
          int slot = ((s*4 + lk) ^ (lr & 7)) * 8;
          short8 af = *(const short8*)&AslLN[(w*16+lr)*520 + kc + s*32 + lk*8];
          #pragma unroll
          for (int nf = 0; nf < 4; nf++){
            short8 bf8 = *(const short8*)&Bs64[(nf*16+lr)*64 + slot];
            acc[nf] = __builtin_amdgcn_mfma_f32_16x16x32_bf16(af, bf8, acc[nf], 0, 0, 0);
          }
        }
      }
      #pragma unroll
      for (int nf = 0; nf < 4; nf++){
        int col = n0 + nf*16 + lr;
        float bsv = A.bf1[l*MM + col];
        #pragma unroll
        for (int jj = 0; jj < 4; jj++){
          int row = w*16 + lk*4 + jj;
          float v = acc[nf][jj] + bsv;
          v = 0.5f*v*(1.f + tanhf(0.7978845608028654f*(v + 0.044715f*v*v*v)));
          A.mid[(size_t)row*MM + col] = f2bf(v);
        }
      }
    } else if (l < LL-1){
      int base = bid - 32;
      for (int j = 0; j < 5; j++){
        int id = base + j*224;
        if (id < 1024) d_wvo(l+1, id, A.Wv, A.Wo, A.WVO, SM, SM + 4096, t);
      }
    }
    gbar(A.bar, bars);

    // ---- P6: x += mid @ W2^T + bf2 (64 blocks, ksplit8) ----
    if (bid < 64){
      int n0 = (bid & 7)*64, ks = bid >> 3;
      const u16* Bt = A.w2T + (size_t)l*DD*MM;
      float4v acc[4]; acc[0]=z4; acc[1]=z4; acc[2]=z4; acc[3]=z4;
      int kbeg = ks*256;
      for (int kc = kbeg; kc < kbeg + 256; kc += 64){
        __syncthreads();
        {
          int sr8 = t >> 3, sl = t & 7;
          int sw = ((sl ^ (sr8 & 7)) * 8);
          gl16(A.mid + (size_t)sr8*MM + kc + sw, SM + 8*t);
          gl16(A.mid + (size_t)(32 + sr8)*MM + kc + sw, SM + 2048 + 8*t);
        }
        d_stageB64(Bt, n0, kc, MM, Bs64, t);
        __syncthreads();
        #pragma unroll
        for (int s = 0; s < 2; s++){
          int slot = ((s*4 + lk) ^ (lr & 7)) * 8;
          short8 af = *(const short8*)&SM[(w*16+lr)*64 + slot];
          #pragma unroll
          for (int nf = 0; nf < 4; nf++){
            short8 bf8 = *(const short8*)&Bs64[(nf*16+lr)*64 + slot];
            acc[nf] = __builtin_amdgcn_mfma_f32_16x16x32_bf16(af, bf8, acc[nf], 0, 0, 0);
          }
        }
      }
      #pragma unroll
      for (int nf = 0; nf < 4; nf++){
        int col = n0 + nf*16 + lr;
        float bsv = (ks == 0) ? A.bf2[l*DD + col] : 0.f;
        #pragma unroll
        for (int jj = 0; jj < 4; jj++){
          int row = w*16 + lk*4 + jj;
          atomicAdd(&A.x[(size_t)row*DD + col], acc[nf][jj] + bsv);
        }
      }
    }
    gbar(A.bar, bars);
  }

  // ---- P7: heads h4 = relu(x @ headsT^T + hb4), hp = bf16(cols>=1536) (32 blocks) ----
  if (bid < 32){
    int n0 = bid*64;
    float4v acc[4]; acc[0]=z4; acc[1]=z4; acc[2]=z4; acc[3]=z4;
    for (int kc = 0; kc < 512; kc += 64){
      __syncthreads();
      {
        int rr = t >> 2, c0 = (t & 3)*16;
        const float* xb = A.x + (size_t)rr*DD + kc + c0;
        float4 f0 = *(const float4*)(xb);
        float4 f1 = *(const float4*)(xb + 4);
        float4 f2 = *(const float4*)(xb + 8);
        float4 f3 = *(const float4*)(xb + 12);
        u16* d = SM + rr*72 + c0;
        d[0]=f2bf(f0.x); d[1]=f2bf(f0.y); d[2]=f2bf(f0.z); d[3]=f2bf(f0.w);
        d[4]=f2bf(f1.x); d[5]=f2bf(f1.y); d[6]=f2bf(f1.z); d[7]=f2bf(f1.w);
        d[8]=f2bf(f2.x); d[9]=f2bf(f2.y); d[10]=f2bf(f2.z); d[11]=f2bf(f2.w);
        d[12]=f2bf(f3.x); d[13]=f2bf(f3.y); d[14]=f2bf(f3.z); d[15]=f2bf(f3.w);
      }
      d_stageB64(A.headsT, n0, kc, DD, Bs64, t);
      __syncthreads();
      #pragma unroll
      for (int s = 0; s < 2; s++){
        int slot = ((s*4 + lk) ^ (lr & 7)) * 8;
        short8 af = *(const short8*)&SM[(w*16+lr)*72 + s*32 + lk*8];
        #pragma unroll
        for (int nf = 0; nf < 4; nf++){
          short8 bf8 = *(const short8*)&Bs64[(nf*16+lr)*64 + slot];
          acc[nf] = __builtin_amdgcn_mfma_f32_16x16x32_bf16(af, bf8, acc[nf], 0, 0, 0);
        }
      }
    }
    #pragma unroll
    for (int nf = 0; nf < 4; nf++){
      int col = n0 + nf*16 + lr;
      float bsv = A.hb4[col];
      #pragma unroll
      for (int jj = 0; jj < 4; jj++){
        int row = w*16 + lk*4 + jj;
        float v = fmaxf(acc[nf][jj] + bsv, 0.f);
        A.h4[(size_t)row*2048 + col] = v;
        if (col >= 1536) A.hp[(size_t)row*DD + col - 1536] = f2bf(v);
      }
    }
  }
  gbar(A.bar, bars);

  // ---- P8: rot6d = hp @ pw2T^T + cvec2 (16 blocks, guard col<978) ----
  if (bid < 16){
    int n0 = bid*64;
    float4v acc[4]; acc[0]=z4; acc[1]=z4; acc[2]=z4; acc[3]=z4;
    for (int kc = 0; kc < 512; kc += 64){
      __syncthreads();
      {
        int sr8 = t >> 3, sl = t & 7;
        int sw = ((sl ^ (sr8 & 7)) * 8);
        gl16(A.hp + (size_t)sr8*DD + kc + sw, SM + 8*t);
        gl16(A.hp + (size_t)(32 + sr8)*DD + kc + sw, SM + 2048 + 8*t);
      }
      d_stageB64(A.pw2T, n0, kc, DD, Bs64, t);
      __syncthreads();
      #pragma unroll
      for (int s = 0; s < 2; s++){
        int slot = ((s*4 + lk) ^ (lr & 7)) * 8;
        short8 af = *(const short8*)&SM[(w*16+lr)*64 + slot];
        #pragma unroll
        for (int nf = 0; nf < 4; nf++){
          short8 bf8 = *(const short8*)&Bs64[(nf*16+lr)*64 + slot];
          acc[nf] = __builtin_amdgcn_mfma_f32_16x16x32_bf16(af, bf8, acc[nf], 0, 0, 0);
        }
      }
    }
    #pragma unroll
    for (int nf = 0; nf < 4; nf++){
      int col = n0 + nf*16 + lr;
      if (col < NROT){
        float bsv = A.cvec2[col];
        #pragma unroll
        for (int jj = 0; jj < 4; jj++){
          int row = w*16 + lk*4 + jj;
          A.rot6d[(size_t)row*NROT + col] = acc[nf][jj] + bsv;
        }
      }
    }
  }
  gbar(A.bar, bars);

  // ---- P9: final assembly (64 blocks) ----
  if (bid < 64){
    int bq = bid, b = bq >> 4;
    float po0 = 0.f, po1 = 0.f, pd = 0.f, ps[11];
    #pragma unroll
    for (int j = 0; j < 11; j++) ps[j] = 0.f;
    const float* hrow = A.h4 + (size_t)bq*2048;
    for (int i = t; i < DD; i += 256){
      float ho = hrow[i];
      float hd = hrow[512 + i];
      float hs = hrow[1024 + i];
      po0 += ho*A.offW2[i*2]; po1 += ho*A.offW2[i*2+1];
      pd += hd*A.dW2[i];
      #pragma unroll
      for (int j = 0; j < 11; j++) ps[j] += hs*A.sW2[i*11+j];
    }
    float vals[14];
    vals[0] = po0; vals[1] = po1; vals[2] = pd;
    #pragma unroll
    for (int j = 0; j < 11; j++) vals[3+j] = ps[j];
    #pragma unroll
    for (int kk = 0; kk < 14; kk++){
      float r = wred_sum(vals[kk]);
      if (lane == 0) SF[w*14 + kk] = r;
    }
    __syncthreads();
    if (t < 14) SF[56 + t] = SF[t] + SF[14+t] + SF[28+t] + SF[42+t];
    __syncthreads();
    float m = A.maskf[bq];
    if (t == 0){
      float off0 = SF[56+0] + A.offb2[0], off1 = SF[56+1] + A.offb2[1];
      float draw = SF[56+2] + A.db2[0];
      float l0 = (A.colf[bq] + 0.5f + off0) * 14.0f;
      float l1 = (A.rowf[bq] + 0.5f + off1) * 14.0f;
      float fx = A.K_cam[b*9+0], cx = A.K_cam[b*9+2], fy = A.K_cam[b*9+4], cy = A.K_cam[b*9+5];
      float dist = fx / fmaxf(expf(draw), 1e-5f);
      float tx = (l0 - cx) / fx * dist, ty = (l1 - cy) / fy * dist;
      float* o = A.out + (size_t)bq*OUTW;
      o[0] = l0*m; o[1] = l1*m; o[2] = off0*m; o[3] = off1*m; o[4] = dist*m;
      o[5] = tx*m; o[6] = ty*m; o[7] = dist*m;
      #pragma unroll
      for (int j = 0; j < 11; j++){ float sp = SF[56+3+j] + A.sb2[j]; o[8+j] = m / (1.f + expf(-sp)); }
    }
    if (t < NJ){
      const float* rp = A.rot6d + (size_t)bq*NROT + t*6;
      float a0 = rp[0], b0 = rp[1], a1 = rp[2], b1 = rp[3], a2 = rp[4], b2 = rp[5];
      float n0 = sqrtf(a0*a0 + a1*a1 + a2*a2);
      float i0 = 1.f / (n0 + 1e-8f);
      float u00 = a0*i0, u01 = a1*i0, u02 = a2*i0;
      float dt = b0*u00 + b1*u01 + b2*u02;
      float v0 = b0 - dt*u00, v1 = b1 - dt*u01, v2 = b2 - dt*u02;
      float n1 = sqrtf(v0*v0 + v1*v1 + v2*v2);
      float i1 = 1.f / (n1 + 1e-8f);
      float u10 = v0*i1, u11 = v1*i1, u12 = v2*i1;
      float u20 = u01*u12 - u02*u11;
      float u21 = u02*u10 - u00*u12;
      float u22 = u00*u11 - u01*u10;
      float um = A.useful[t], om = 1.f - um;
      float R00 = um*u00 + om, R01 = um*u10,      R02 = um*u20;
      float R10 = um*u01,      R11 = um*u11 + om, R12 = um*u21;
      float R20 = um*u02,      R21 = um*u12,      R22 = um*u22 + om;
      float* o = A.out + (size_t)bq*OUTW + 19 + t*9;
      o[0] = R00*m; o[1] = R01*m; o[2] = R02*m;
      o[3] = R10*m; o[4] = R11*m; o[5] = R12*m;
      o[6] = R20*m; o[7] = R21*m; o[8] = R22*m;
    }
  }
}

extern "C" void kernel_launch(void* const* d_in, const int* in_sizes, int n_in,
                              void* d_out, int out_size, void* d_ws, size_t ws_size,
                              hipStream_t stream)
{
  const float* feat   = (const float*)d_in[0];
  const float* scores = (const float*)d_in[1];
  const float* K_cam  = (const float*)d_in[2];
  const float* pos_emb= (const float*)d_in[3];
  const float* Wtok   = (const float*)d_in[4];
  const float* btok   = (const float*)d_in[5];
  const float* Wq     = (const float*)d_in[6];
  const float* Wk     = (const float*)d_in[7];
  const float* Wv     = (const float*)d_in[8];
  const float* Wo     = (const float*)d_in[9];
  const float* g1     = (const float*)d_in[10];
  const float* b1n    = (const float*)d_in[11];
  const float* W1     = (const float*)d_in[12];
  const float* bf1    = (const float*)d_in[13];
  const float* W2     = (const float*)d_in[14];
  const float* bf2    = (const float*)d_in[15];
  const float* g2     = (const float*)d_in[16];
  const float* b2n    = (const float*)d_in[17];
  const float* offW1  = (const float*)d_in[18];
  const float* offb1  = (const float*)d_in[19];
  const float* offW2  = (const float*)d_in[20];
  const float* offb2  = (const float*)d_in[21];
  const float* dW1    = (const float*)d_in[22];
  const float* db1    = (const float*)d_in[23];
  const float* dW2    = (const float*)d_in[24];
  const float* db2    = (const float*)d_in[25];
  const float* sW1    = (const float*)d_in[26];
  const float* sb1    = (const float*)d_in[27];
  const float* sW2    = (const float*)d_in[28];
  const float* sb2    = (const float*)d_in[29];
  const float* pW1    = (const float*)d_in[30];
  const float* pb1    = (const float*)d_in[31];
  const float* pW2    = (const float*)d_in[32];
  const float* pb2    = (const float*)d_in[33];
  const float* ibp    = (const float*)d_in[34];
  const float* useful = (const float*)d_in[35];
  float* out = (float*)d_out;

  char* wsp = (char*)d_ws;
  size_t off = 0;
  auto alloc = [&](size_t bytes)->char*{
    char* p = wsp + off;
    off += (bytes + 255) & ~((size_t)255);
    return p;
  };
  int*   t_idx  = (int*)  alloc(BKQ*4);
  float* t_mask = (float*)alloc(BKQ*4);
  float* t_col  = (float*)alloc(BKQ*4);
  float* t_row  = (float*)alloc(BKQ*4);
  int*   barp   = (int*)  alloc(256);
  u16*   feat_bf= (u16*)  alloc((size_t)BB*TOK*CE*2);
  u16*   wtokT  = (u16*)  alloc((size_t)DD*CE*2);
  u16*   ctx_bf = (u16*)  alloc((size_t)BB*TOK*DD*2);
  u16*   ctxT_bf= (u16*)  alloc((size_t)BB*TOK*DD*2);
  u16*   ATb    = (u16*)  alloc((size_t)8192*DD*2);
  u16*   WVOb   = (u16*)  alloc((size_t)DD*8192*2);
  u16*   w1T    = (u16*)  alloc((size_t)LL*DD*MM*2);
  u16*   w2T    = (u16*)  alloc((size_t)LL*MM*DD*2);
  u16*   headsT = (u16*)  alloc((size_t)4*DD*DD*2);
  u16*   pw2T   = (u16*)  alloc((size_t)1024*DD*2);
  float* x      = (float*)alloc((size_t)BKQ*DD*4);
  u16*   z      = (u16*)  alloc((size_t)BKQ*8192*2);
  float* logits = (float*)alloc((size_t)BB*QH*TOK*4);   // also PV partials
  u16*   att    = (u16*)  alloc((size_t)BB*QH*TOK*2);
  u16*   mid    = (u16*)  alloc((size_t)BKQ*MM*2);
  float* h4     = (float*)alloc((size_t)BKQ*2048*4);
  u16*   hp     = (u16*)  alloc((size_t)BKQ*DD*2);
  float* hb4    = (float*)alloc(2048*4);
  float* cvec2  = (float*)alloc(1024*4);
  float* rot6d  = (float*)alloc((size_t)BKQ*NROT*4);
  if (off > ws_size) return;

  // job table for unified weight transposer
  PJobs J;
  int ntl = 0, nj = 0;
  auto addjob = [&](const float* s, u16* d, int R, int C){
    J.s[nj] = s; J.d[nj] = d; J.R[nj] = R; J.C[nj] = C; J.t0[nj] = ntl;
    ntl += ((R+31)/32) * ((C+31)/32);
    nj++;
  };
  addjob(Wtok, wtokT, CE, DD);
  for (int l = 0; l < LL; l++) addjob(W1 + (size_t)l*DD*MM, w1T + (size_t)l*MM*DD, DD, MM);
  for (int l = 0; l < LL; l++) addjob(W2 + (size_t)l*MM*DD, w2T + (size_t)l*DD*MM, MM, DD);
  addjob(offW1, headsT,            DD, DD);
  addjob(dW1,   headsT + DD*DD,    DD, DD);
  addjob(sW1,   headsT + 2*DD*DD,  DD, DD);
  addjob(pW1,   headsT + 3*DD*DD,  DD, DD);   // first 512 rows of pW1
  addjob(pW2,   pw2T, DD, NROT);
  J.t0[nj] = ntl; J.njobs = nj; J.ntiles = ntl;

  k_nms_topk<<<BB, 256, 0, stream>>>(scores, t_idx, t_mask, t_col, t_row);
  k_cvt_bf16<<<3072, 256, 0, stream>>>(feat, feat_bf, BB*TOK*CE/4);
  k_prepw<<<2048, 256, 0, stream>>>(J);
  k_gemm_emb<<<dim3(DD/128, (BB*TOK)/128, 1), 256, 0, stream>>>(feat_bf, wtokT, ctx_bf, btok, pos_emb);
  k_transp_b<<<dim3(DD/32, TOK/32, BB), 256, 0, stream>>>(ctx_bf, ctxT_bf, TOK, DD);
  k_misc<<<193, 256, 0, stream>>>(feat, Wtok, btok, pos_emb, t_idx, x, pW1, pb1, ibp, hb4,
                                  offb1, db1, sb1, pb2, cvec2);
  hipMemsetAsync(barp, 0, 256, stream);

  MG A;
  A.x = x; A.z = z; A.ctx = ctx_bf; A.ctxT = ctxT_bf;
  A.logits = logits; A.att = att; A.mid = mid;
  A.AT = ATb; A.WVO = WVOb;
  A.w1T = w1T; A.w2T = w2T;
  A.Wq = Wq; A.Wk = Wk; A.Wv = Wv; A.Wo = Wo;
  A.g1 = g1; A.b1n = b1n; A.g2 = g2; A.b2n = b2n;
  A.bf1 = bf1; A.bf2 = bf2;
  A.headsT = headsT; A.hb4 = hb4; A.pw2T = pw2T; A.cvec2 = cvec2;
  A.h4 = h4; A.hp = hp; A.rot6d = rot6d;
  A.offW2 = offW2; A.offb2 = offb2; A.dW2 = dW2; A.db2 = db2;
  A.sW2 = sW2; A.sb2 = sb2; A.K_cam = K_cam; A.useful = useful;
  A.maskf = t_mask; A.colf = t_col; A.rowf = t_row; A.out = out;
  A.bar = barp;
  k_layers<<<NBLK, 256, 0, stream>>>(A);
}

// Round 7
// 1257.693 us; speedup vs baseline: 3.4332x; 3.4332x over previous
//
#include <hip/hip_runtime.h>

typedef unsigned int uint;
typedef unsigned short u16;

#define BB 4
#define CE 384
#define DD 512
#define LL 8
#define HH 16
#define MM 2048
#define NJ 163
#define TOK 4096
#define BKQ 64
#define QH 256
#define OUTW 1486
#define NROT 978

typedef __attribute__((ext_vector_type(8))) short short8;
typedef __attribute__((ext_vector_type(4))) float float4v;

static __device__ __forceinline__ u16 f2bf(float f){
  union { float f; uint u; } c; c.f = f;
  uint u = c.u;
  return (u16)((u + 0x7FFFu + ((u >> 16) & 1u)) >> 16);
}
static __device__ __forceinline__ float bf2f(u16 u){
  union { uint u; float f; } c; c.u = ((uint)u) << 16;
  return c.f;
}
static __device__ __forceinline__ float wred_sum(float v){
  for (int o = 32; o; o >>= 1) v += __shfl_xor(v, o, 64);
  return v;
}
static __device__ __forceinline__ void gl16(const void* g, void* l){
  __builtin_amdgcn_global_load_lds((const __attribute__((address_space(1))) void*)g,
                                   (__attribute__((address_space(3))) void*)l, 16, 0, 0);
}

// ---------------- NMS + top-k (register scan, exact fp32, stable ties) ----------------
__global__ __launch_bounds__(256) void k_nms_topk(const float* __restrict__ scores,
    int* __restrict__ oidx, float* __restrict__ omask, float* __restrict__ ocol, float* __restrict__ orow)
{
  int b = blockIdx.x, t = threadIdx.x;
  __shared__ float sraw[4096];
  __shared__ float sv[4]; __shared__ int si[4]; __shared__ int swin;
  const float* sp = scores + (size_t)b * 4096;
  for (int i = t; i < 4096; i += 256) sraw[i] = sp[i];
  __syncthreads();
  float v[16];
  #pragma unroll
  for (int j = 0; j < 16; j++){
    int i = t + j*256;
    int r = i >> 6, c = i & 63;
    float mx = -1e30f;
    for (int dr = -1; dr <= 1; dr++){
      int rr = r + dr; if (rr < 0 || rr > 63) continue;
      for (int dc = -1; dc <= 1; dc++){
        int cc = c + dc; if (cc < 0 || cc > 63) continue;
        mx = fmaxf(mx, sraw[rr*64+cc]);
      }
    }
    float s = sraw[i];
    v[j] = (s == mx) ? s : 0.0f;
  }
  int lane = t & 63, wv = t >> 6;
  for (int iter = 0; iter < 16; iter++){
    float best = -1e30f; int bi_ = 1 << 30;
    #pragma unroll
    for (int j = 0; j < 16; j++){
      if (v[j] > best){ best = v[j]; bi_ = t + j*256; }
    }
    #pragma unroll
    for (int o = 32; o; o >>= 1){
      float ov = __shfl_xor(best, o, 64);
      int oi = __shfl_xor(bi_, o, 64);
      if (ov > best || (ov == best && oi < bi_)){ best = ov; bi_ = oi; }
    }
    if (lane == 0){ sv[wv] = best; si[wv] = bi_; }
    __syncthreads();
    if (t == 0){
      float bb = sv[0]; int ii = si[0];
      for (int k = 1; k < 4; k++){
        if (sv[k] > bb || (sv[k] == bb && si[k] < ii)){ bb = sv[k]; ii = si[k]; }
      }
      oidx[b*16+iter] = ii;
      omask[b*16+iter] = (bb >= 0.3f) ? 1.f : 0.f;
      ocol[b*16+iter] = (float)(ii & 63);
      orow[b*16+iter] = (float)(ii >> 6);
      swin = ii;
    }
    __syncthreads();
    int wi = swin;
    if ((wi & 255) == t) v[wi >> 8] = -1e30f;
    __syncthreads();
  }
}

// ---------------- fp32 -> bf16 convert ----------------
__global__ __launch_bounds__(256) void k_cvt_bf16(const float* __restrict__ in, u16* __restrict__ out, int n4){
  int i = blockIdx.x*256 + threadIdx.x;
  int stride = gridDim.x*256;
  for (int j = i; j < n4; j += stride){
    float4 v = ((const float4*)in)[j];
    ushort4 o;
    o.x = f2bf(v.x); o.y = f2bf(v.y); o.z = f2bf(v.z); o.w = f2bf(v.w);
    ((ushort4*)out)[j] = o;
  }
}

// ---------------- unified transpose+convert: up to 24 jobs fp32(R,C)->bf16(C,R) ----------------
struct PJobs {
  const float* s[24]; u16* d[24];
  int R[24], C[24], t0[25];
  int njobs, ntiles;
};
__global__ __launch_bounds__(256) void k_prepw(PJobs J){
  __shared__ float tile[32][33];
  for (int g = blockIdx.x; g < J.ntiles; g += gridDim.x){
    int j = 0;
    while (g >= J.t0[j+1]) j++;
    int ti = g - J.t0[j];
    int C_ = J.C[j], R_ = J.R[j];
    int tC = (C_ + 31) >> 5;
    int ry = ti / tC, cx = ti - ry*tC;
    int c0 = cx*32, r0 = ry*32;
    int tx = threadIdx.x & 31, ty = threadIdx.x >> 5;
    const float* src = J.s[j]; u16* dst = J.d[j];
    for (int i = 0; i < 32; i += 8){
      float v = 0.f;
      if (c0+tx < C_) v = src[(size_t)(r0+ty+i)*C_ + c0+tx];
      tile[ty+i][tx] = v;
    }
    __syncthreads();
    for (int i = 0; i < 32; i += 8){
      if (c0+ty+i < C_) dst[(size_t)(c0+ty+i)*R_ + r0+tx] = f2bf(tile[tx][ty+i]);
    }
    __syncthreads();
  }
}

// ---------------- batched (per-layer) transpose+convert fp32(R,C)->bf16(C,R) ----------------
__global__ __launch_bounds__(256) void k_tconvL(const float* __restrict__ in, u16* __restrict__ out, int R, int C){
  in  += (size_t)blockIdx.z * R * C;
  out += (size_t)blockIdx.z * R * C;
  __shared__ float tile[32][33];
  int c0 = blockIdx.x*32, r0 = blockIdx.y*32;
  int tx = threadIdx.x & 31, ty = threadIdx.x >> 5;
  for (int i = 0; i < 32; i += 8) tile[ty+i][tx] = in[(size_t)(r0+ty+i)*C + c0+tx];
  __syncthreads();
  for (int i = 0; i < 32; i += 8) out[(size_t)(c0+ty+i)*R + r0+tx] = f2bf(tile[tx][ty+i]);
}

// ---------------- bf16 transpose (R,C) -> (C,R), batched in z ----------------
__global__ __launch_bounds__(256) void k_transp_b(const u16* __restrict__ in, u16* __restrict__ out, int R, int C){
  in  += (size_t)blockIdx.z * R * C;
  out += (size_t)blockIdx.z * R * C;
  __shared__ u16 tile[32][33];
  int c0 = blockIdx.x*32, r0 = blockIdx.y*32;
  int tx = threadIdx.x & 31, ty = threadIdx.x >> 5;
  for (int i = 0; i < 32; i += 8) tile[ty+i][tx] = in[(size_t)(r0+ty+i)*C + c0+tx];
  __syncthreads();
  for (int i = 0; i < 32; i += 8) out[(size_t)(c0+ty+i)*R + r0+tx] = tile[tx][ty+i];
}

// ---------------- ctx embed GEMM: ctx = feat_bf @ wtokT^T + btok + pos_emb -> bf16 ----------------
__global__ __launch_bounds__(256) void k_gemm_emb(
    const u16* __restrict__ A, const u16* __restrict__ Bt, u16* __restrict__ Cb,
    const float* __restrict__ ep1, const float* __restrict__ ep2)
{
  int m0 = blockIdx.y*128, n0 = blockIdx.x*128;
  __shared__ __align__(16) u16 As[128*64];
  __shared__ __align__(16) u16 Bs[128*64];
  int t = threadIdx.x, lane = t & 63, wave = t >> 6;
  int wr = wave >> 1, wc = wave & 1;
  int lr = lane & 15, lk = lane >> 4;
  int sr8 = t >> 3, sl = t & 7;
  int sw = ((sl ^ (sr8 & 7)) * 8);
  float4v acc[4][4];
  float4v z4 = {0.f, 0.f, 0.f, 0.f};
  #pragma unroll
  for (int i = 0; i < 4; i++)
    #pragma unroll
    for (int j = 0; j < 4; j++) acc[i][j] = z4;
  for (int kt = 0; kt < CE; kt += 64){
    __syncthreads();
    #pragma unroll
    for (int rg = 0; rg < 4; rg++){
      gl16(A + (size_t)(m0 + rg*32 + sr8)*CE + kt + sw, As + rg*2048 + 8*t);
      gl16(Bt + (size_t)(n0 + rg*32 + sr8)*CE + kt + sw, Bs + rg*2048 + 8*t);
    }
    __syncthreads();
    #pragma unroll
    for (int s = 0; s < 2; s++){
      int slot = ((s*4 + lk) ^ (lr & 7)) * 8;
      short8 af[4], bfr[4];
      #pragma unroll
      for (int i = 0; i < 4; i++) af[i] = *(const short8*)&As[(wr*64 + i*16 + lr)*64 + slot];
      #pragma unroll
      for (int j = 0; j < 4; j++) bfr[j] = *(const short8*)&Bs[(wc*64 + j*16 + lr)*64 + slot];
      #pragma unroll
      for (int i = 0; i < 4; i++)
        #pragma unroll
        for (int j = 0; j < 4; j++)
          acc[i][j] = __builtin_amdgcn_mfma_f32_16x16x32_bf16(af[i], bfr[j], acc[i][j], 0, 0, 0);
    }
  }
  #pragma unroll
  for (int i = 0; i < 4; i++){
    int rbase = m0 + wr*64 + i*16 + lk*4;
    #pragma unroll
    for (int j = 0; j < 4; j++){
      int cc = n0 + wc*64 + j*16 + lr;
      #pragma unroll
      for (int jj = 0; jj < 4; jj++){
        int rr = rbase + jj;
        float vv = acc[i][j][jj] + ep1[cc] + ep2[(size_t)(rr & 4095)*DD + cc];
        Cb[(size_t)rr*DD + cc] = f2bf(vv);
      }
    }
  }
}

// ---------------- misc: gather + pose-const + bias packing ----------------
__global__ __launch_bounds__(256) void k_misc(const float* __restrict__ feat, const float* __restrict__ Wtok,
    const float* __restrict__ btok, const float* __restrict__ pos_emb, const int* __restrict__ oidx,
    float* __restrict__ x, const float* __restrict__ pW1, const float* __restrict__ pb1,
    const float* __restrict__ ibp, float* __restrict__ hb4,
    const float* __restrict__ offb1, const float* __restrict__ db1, const float* __restrict__ sb1,
    const float* __restrict__ pb2, float* __restrict__ cvec2)
{
  int bid = blockIdx.x, t = threadIdx.x;
  if (bid < 64){
    int b = bid >> 4, tok = oidx[bid];
    __shared__ float fs[CE];
    const float* fr = feat + ((size_t)b*TOK + tok) * CE;
    for (int i = t; i < CE; i += 256) fs[i] = fr[i];
    __syncthreads();
    for (int d = t; d < DD; d += 256){
      float acc = btok[d] + pos_emb[(size_t)tok*DD + d];
      for (int i = 0; i < CE; i++) acc += fs[i] * Wtok[(size_t)i*DD + d];
      x[(size_t)bid*DD + d] = acc;
    }
  } else if (bid < 192){
    int d = (bid - 64)*4 + (t >> 6);
    int ln = t & 63;
    float acc = 0.f;
    for (int i = ln; i < NJ*6; i += 64) acc += ibp[i] * pW1[(size_t)(DD+i)*DD + d];
    acc = wred_sum(acc);
    if (ln == 0) hb4[1536 + d] = acc + pb1[d];
  } else {
    for (int i = t; i < 1536; i += 256)
      hb4[i] = (i < 512) ? offb1[i] : (i < 1024 ? db1[i-512] : sb1[i-1024]);
    for (int i = t; i < 1024; i += 256)
      cvec2[i] = (i < NJ*6) ? (pb2[i] + ibp[i]) : 0.f;
  }
}

// ---------------- MFMA GEMM, 128(M) x 64(N) tiles: C = A(MxK) @ Bt(NxK)^T ----------------
// EPI 0: fp32 store into slice bz (split-K partials).  EPI 1: bf16 store into batch slice.
template<int EPI>
__global__ __launch_bounds__(256) void k_gemm_bt64(
    const u16* __restrict__ A, const u16* __restrict__ Bt,
    float* __restrict__ C, u16* __restrict__ Cb,
    int Kslice, int lda, int ldb, int ldc,
    long sA, long sB, long sC, int ksplit)
{
  int bz = blockIdx.z;
  int batch = bz / ksplit, ks = bz - batch*ksplit;
  const u16* Ab = A + (size_t)batch*sA + (size_t)ks*Kslice;
  const u16* Bb = Bt + (size_t)batch*sB + (size_t)ks*Kslice;
  int m0 = blockIdx.y*128, n0 = blockIdx.x*64;
  __shared__ __align__(16) u16 As[128*64];
  __shared__ __align__(16) u16 Bs[64*64];
  int t = threadIdx.x, lane = t & 63, w = t >> 6;
  int lr = lane & 15, lk = lane >> 4;
  int sr8 = t >> 3, sl = t & 7;
  int sw = ((sl ^ (sr8 & 7)) * 8);
  float4v acc[2][4];
  float4v z4 = {0.f,0.f,0.f,0.f};
  #pragma unroll
  for (int i = 0; i < 2; i++)
    #pragma unroll
    for (int j = 0; j < 4; j++) acc[i][j] = z4;

  for (int kt = 0; kt < Kslice; kt += 64){
    __syncthreads();
    #pragma unroll
    for (int rg = 0; rg < 4; rg++)
      gl16(Ab + (size_t)(m0 + rg*32 + sr8)*lda + kt + sw, As + rg*2048 + 8*t);
    #pragma unroll
    for (int rg = 0; rg < 2; rg++)
      gl16(Bb + (size_t)(n0 + rg*32 + sr8)*ldb + kt + sw, Bs + rg*2048 + 8*t);
    __syncthreads();
    #pragma unroll
    for (int s = 0; s < 2; s++){
      int slot = ((s*4 + lk) ^ (lr & 7)) * 8;
      short8 af[2], bfr[4];
      #pragma unroll
      for (int i = 0; i < 2; i++) af[i] = *(const short8*)&As[(w*32 + i*16 + lr)*64 + slot];
      #pragma unroll
      for (int j = 0; j < 4; j++) bfr[j] = *(const short8*)&Bs[(j*16 + lr)*64 + slot];
      #pragma unroll
      for (int i = 0; i < 2; i++)
        #pragma unroll
        for (int j = 0; j < 4; j++)
          acc[i][j] = __builtin_amdgcn_mfma_f32_16x16x32_bf16(af[i], bfr[j], acc[i][j], 0, 0, 0);
    }
  }
  #pragma unroll
  for (int i = 0; i < 2; i++){
    int rbase = m0 + w*32 + i*16 + lk*4;
    #pragma unroll
    for (int j = 0; j < 4; j++){
      int cc = n0 + j*16 + lr;
      #pragma unroll
      for (int jj = 0; jj < 4; jj++){
        int rr = rbase + jj;
        if (EPI == 0) C[(size_t)bz*sC + (size_t)rr*ldc + cc] = acc[i][j][jj];
        else Cb[(size_t)batch*sC + (size_t)rr*ldc + cc] = f2bf(acc[i][j][jj]);
      }
    }
  }
}

// ---------------- skinny MFMA GEMM: C(64 x N) = A(64 x K) @ Bt(N x K)^T ----------------
// ACT: 0 none, 1 relu, 2 gelu.  RES: 0 store, 1 atomicAdd.  OUTB: bf16 out.
// DOLN: A = LN(xf)*g+b computed in-block.  NG: guard col<N.  HPB: bf16 copy of cols>=1536.
template<int ACT, int RES, int OUTB, int DOLN, int NG, int HPB>
__global__ __launch_bounds__(256) void k_mf64(
    const u16* __restrict__ A, const float* __restrict__ xf,
    const float* __restrict__ g, const float* __restrict__ bb,
    const u16* __restrict__ Bt, const float* __restrict__ bias,
    float* __restrict__ C, u16* __restrict__ Cb, u16* __restrict__ Cb2,
    int N, int K, int kper, int ldc, float alpha)
{
  __shared__ __align__(16) u16 Asl[DOLN ? 64*520 : 64*64];
  __shared__ __align__(16) u16 Bs[64*64];
  int t = threadIdx.x, lane = t & 63, w = t >> 6;
  int lr = lane & 15, lk = lane >> 4;
  int n0 = blockIdx.x*64;
  int ks = blockIdx.y, kbeg = ks*kper;
  int sr8 = t >> 3, sl = t & 7;
  int sw = ((sl ^ (sr8 & 7)) * 8);

  if (DOLN){
    for (int rr = 0; rr < 16; rr++){
      int row = w*16 + rr;
      const float* xr = xf + (size_t)row*DD;
      float4 v0 = *(const float4*)(xr + lane*4);
      float4 v1 = *(const float4*)(xr + 256 + lane*4);
      float s = v0.x+v0.y+v0.z+v0.w + v1.x+v1.y+v1.z+v1.w;
      s = wred_sum(s);
      float mu = s * (1.f/DD);
      float d0=v0.x-mu, d1=v0.y-mu, d2=v0.z-mu, d3=v0.w-mu;
      float e0=v1.x-mu, e1=v1.y-mu, e2=v1.z-mu, e3=v1.w-mu;
      float q = d0*d0+d1*d1+d2*d2+d3*d3 + e0*e0+e1*e1+e2*e2+e3*e3;
      q = wred_sum(q);
      float inv = rsqrtf(q * (1.f/DD) + 1e-5f);
      float4 g0 = *(const float4*)(g + lane*4);
      float4 g1 = *(const float4*)(g + 256 + lane*4);
      float4 b0 = *(const float4*)(bb + lane*4);
      float4 b1 = *(const float4*)(bb + 256 + lane*4);
      u16* dst = &Asl[row*520];
      dst[lane*4+0] = f2bf(d0*inv*g0.x + b0.x);
      dst[lane*4+1] = f2bf(d1*inv*g0.y + b0.y);
      dst[lane*4+2] = f2bf(d2*inv*g0.z + b0.z);
      dst[lane*4+3] = f2bf(d3*inv*g0.w + b0.w);
      dst[256+lane*4+0] = f2bf(e0*inv*g1.x + b1.x);
      dst[256+lane*4+1] = f2bf(e1*inv*g1.y + b1.y);
      dst[256+lane*4+2] = f2bf(e2*inv*g1.z + b1.z);
      dst[256+lane*4+3] = f2bf(e3*inv*g1.w + b1.w);
    }
  }

  float4v acc[4];
  float4v z4 = {0.f,0.f,0.f,0.f};
  acc[0]=z4; acc[1]=z4; acc[2]=z4; acc[3]=z4;

  for (int kc = kbeg; kc < kbeg + kper; kc += 64){
    __syncthreads();
    if (!DOLN){
      gl16(A + (size_t)sr8*K + kc + sw,        (u16*)Asl + 8*t);
      gl16(A + (size_t)(32+sr8)*K + kc + sw,   (u16*)Asl + 2048 + 8*t);
    }
    gl16(Bt + (size_t)(n0+sr8)*K + kc + sw,      (u16*)Bs + 8*t);
    gl16(Bt + (size_t)(n0+32+sr8)*K + kc + sw,   (u16*)Bs + 2048 + 8*t);
    __syncthreads();
    #pragma unroll
    for (int s = 0; s < 2; s++){
      int slot = ((s*4 + lk) ^ (lr & 7)) * 8;
      short8 af;
      if (DOLN) af = *(const short8*)&Asl[(w*16+lr)*520 + kc + s*32 + lk*8];
      else      af = *(const short8*)&Asl[(w*16+lr)*64 + slot];
      #pragma unroll
      for (int nf = 0; nf < 4; nf++){
        short8 bf8 = *(const short8*)&Bs[(nf*16+lr)*64 + slot];
        acc[nf] = __builtin_amdgcn_mfma_f32_16x16x32_bf16(af, bf8, acc[nf], 0, 0, 0);
      }
    }
  }
  #pragma unroll
  for (int nf = 0; nf < 4; nf++){
    int col = n0 + nf*16 + lr;
    float bsv = (bias && ks == 0) ? bias[col] : 0.f;
    #pragma unroll
    for (int jj = 0; jj < 4; jj++){
      int row = w*16 + lk*4 + jj;
      float v = acc[nf][jj]*alpha + bsv;
      if (ACT == 1) v = fmaxf(v, 0.f);
      else if (ACT == 2) v = 0.5f*v*(1.f + tanhf(0.7978845608028654f*(v + 0.044715f*v*v*v)));
      if (NG && col >= N) continue;
      size_t o = (size_t)row*ldc + col;
      if (OUTB == 1) Cb[o] = f2bf(v);
      else if (RES == 0) C[o] = v;
      else atomicAdd(&C[o], v);
      if (HPB && col >= 1536) Cb2[(size_t)row*DD + (col - 1536)] = f2bf(v);
    }
  }
}

// ---------------- z[bq][h][d] = sum_dh u[bq][h*32+dh] * Wk[d][h*32+dh]  (bf16 out) ----------------
__global__ __launch_bounds__(256) void k_zker(const float* __restrict__ u, const float* __restrict__ Wk, u16* __restrict__ z){
  int ds = blockIdx.x, h = blockIdx.y, t = threadIdx.x;
  __shared__ float us[64*33];
  __shared__ float wks[128*33];
  for (int idx = t; idx < 2048; idx += 256){ int bq = idx >> 5, dh = idx & 31; us[bq*33+dh] = u[(size_t)bq*DD + h*32 + dh]; }
  for (int idx = t; idx < 4096; idx += 256){ int r = idx >> 5, dh = idx & 31; wks[r*33+dh] = Wk[(size_t)(ds*128+r)*DD + h*32 + dh]; }
  __syncthreads();
  for (int oi = t; oi < 8192; oi += 256){
    int d = oi & 127, bq = oi >> 7;
    float acc = 0.f;
    #pragma unroll
    for (int dh = 0; dh < 32; dh++) acc += us[bq*33+dh] * wks[d*33+dh];
    z[((size_t)bq*HH + h)*DD + ds*128 + d] = f2bf(acc);
  }
}

// ---------------- softmax over 4096, bf16 in -> bf16 probs (packed uint IO) ----------------
__global__ __launch_bounds__(256) void k_softmax(const u16* __restrict__ lg, u16* __restrict__ att){
  int row = blockIdx.x, t = threadIdx.x;
  const uint* p = (const uint*)(lg + (size_t)row*TOK);
  uint pv[8]; float v0[8], v1[8]; float mx = -1e30f;
  #pragma unroll
  for (int i = 0; i < 8; i++){
    pv[i] = p[t + i*256];
    v0[i] = bf2f((u16)(pv[i] & 0xFFFF));
    v1[i] = bf2f((u16)(pv[i] >> 16));
    mx = fmaxf(mx, fmaxf(v0[i], v1[i]));
  }
  int lane = t & 63, w = t >> 6;
  for (int o = 32; o; o >>= 1) mx = fmaxf(mx, __shfl_xor(mx, o, 64));
  __shared__ float sm[4]; __shared__ float ssum[4];
  if (lane == 0) sm[w] = mx;
  __syncthreads();
  mx = fmaxf(fmaxf(sm[0], sm[1]), fmaxf(sm[2], sm[3]));
  float s = 0.f;
  #pragma unroll
  for (int i = 0; i < 8; i++){
    v0[i] = expf(v0[i] - mx); v1[i] = expf(v1[i] - mx);
    s += v0[i] + v1[i];
  }
  s = wred_sum(s);
  if (lane == 0) ssum[w] = s;
  __syncthreads();
  s = ssum[0]+ssum[1]+ssum[2]+ssum[3];
  float inv = 1.f / s;
  uint* q = (uint*)(att + (size_t)row*TOK);
  #pragma unroll
  for (int i = 0; i < 8; i++){
    uint lo = f2bf(v0[i]*inv);
    uint hi = f2bf(v1[i]*inv);
    q[t + i*256] = lo | (hi << 16);
  }
}

// ---------------- o_pre[bq][h*32+dh] = sum_D (Σ_s P)[bq][h][D] * Wv[D][h*32+dh]  (bf16 out) ----------------
__global__ __launch_bounds__(256) void k_ovp(const float* __restrict__ P, const float* __restrict__ Wv, u16* __restrict__ op){
  int bg = blockIdx.x, h = blockIdx.y, t = threadIdx.x;
  __shared__ float wvs[128*33];
  __shared__ float cs[16*129];
  int dh = t & 31, bl = t >> 5;
  float acc0 = 0.f, acc1 = 0.f;
  for (int Dc = 0; Dc < DD; Dc += 128){
    __syncthreads();
    for (int idx = t; idx < 4096; idx += 256){ int r = idx >> 5, q = idx & 31; wvs[r*33+q] = Wv[(size_t)(Dc+r)*DD + h*32 + q]; }
    for (int idx = t; idx < 2048; idx += 256){
      int r = idx >> 7, k = idx & 127;
      size_t base = ((size_t)(bg*8))*((size_t)QH*DD) + (size_t)(r*16+h)*DD + Dc + k;
      float s = 0.f;
      #pragma unroll
      for (int sp = 0; sp < 8; sp++) s += P[base + (size_t)sp*((size_t)QH*DD)];
      cs[r*129+k] = s;
    }
    __syncthreads();
    #pragma unroll 4
    for (int k = 0; k < 128; k++){
      float wv = wvs[k*33+dh];
      acc0 += cs[bl*129 + k] * wv;
      acc1 += cs[(bl+8)*129 + k] * wv;
    }
  }
  op[(size_t)(bg*16+bl)*DD + h*32 + dh] = f2bf(acc0);
  op[(size_t)(bg*16+bl+8)*DD + h*32 + dh] = f2bf(acc1);
}

// ---------------- final heads + Gram-Schmidt + assembly ----------------
__global__ __launch_bounds__(256) void k_final(
    const float* __restrict__ h4, const float* __restrict__ rot6d,
    const float* __restrict__ offW2, const float* __restrict__ offb2,
    const float* __restrict__ dW2, const float* __restrict__ db2,
    const float* __restrict__ sW2, const float* __restrict__ sb2,
    const float* __restrict__ K_cam, const float* __restrict__ useful,
    const float* __restrict__ maskf, const float* __restrict__ colf, const float* __restrict__ rowf,
    float* __restrict__ out)
{
  int bq = blockIdx.x, t = threadIdx.x, b = bq >> 4;
  float po0 = 0.f, po1 = 0.f, pd = 0.f, ps[11];
  #pragma unroll
  for (int j = 0; j < 11; j++) ps[j] = 0.f;
  const float* hrow = h4 + (size_t)bq*2048;
  for (int i = t; i < DD; i += 256){
    float ho = hrow[i];
    float hd = hrow[512 + i];
    float hs = hrow[1024 + i];
    po0 += ho*offW2[i*2]; po1 += ho*offW2[i*2+1];
    pd += hd*dW2[i];
    #pragma unroll
    for (int j = 0; j < 11; j++) ps[j] += hs*sW2[i*11+j];
  }
  __shared__ float sred[4][14];
  __shared__ float sout[14];
  int wv = t >> 6, ln = t & 63;
  float vals[14];
  vals[0] = po0; vals[1] = po1; vals[2] = pd;
  #pragma unroll
  for (int j = 0; j < 11; j++) vals[3+j] = ps[j];
  #pragma unroll
  for (int kk = 0; kk < 14; kk++){
    float r = wred_sum(vals[kk]);
    if (ln == 0) sred[wv][kk] = r;
  }
  __syncthreads();
  if (t < 14) sout[t] = sred[0][t]+sred[1][t]+sred[2][t]+sred[3][t];
  __syncthreads();
  float m = maskf[bq];
  if (t == 0){
    float off0 = sout[0] + offb2[0], off1 = sout[1] + offb2[1];
    float draw = sout[2] + db2[0];
    float l0 = (colf[bq] + 0.5f + off0) * 14.0f;
    float l1 = (rowf[bq] + 0.5f + off1) * 14.0f;
    float fx = K_cam[b*9+0], cx = K_cam[b*9+2], fy = K_cam[b*9+4], cy = K_cam[b*9+5];
    float dist = fx / fmaxf(expf(draw), 1e-5f);
    float tx = (l0 - cx) / fx * dist, ty = (l1 - cy) / fy * dist;
    float* o = out + (size_t)bq*OUTW;
    o[0] = l0*m; o[1] = l1*m; o[2] = off0*m; o[3] = off1*m; o[4] = dist*m;
    o[5] = tx*m; o[6] = ty*m; o[7] = dist*m;
    #pragma unroll
    for (int j = 0; j < 11; j++){ float sp = sout[3+j] + sb2[j]; o[8+j] = m / (1.f + expf(-sp)); }
  }
  if (t < NJ){
    const float* rp = rot6d + (size_t)bq*NROT + t*6;
    float a0 = rp[0], b0 = rp[1], a1 = rp[2], b1 = rp[3], a2 = rp[4], b2 = rp[5];
    float n0 = sqrtf(a0*a0 + a1*a1 + a2*a2);
    float i0 = 1.f / (n0 + 1e-8f);
    float u00 = a0*i0, u01 = a1*i0, u02 = a2*i0;
    float dt = b0*u00 + b1*u01 + b2*u02;
    float v0 = b0 - dt*u00, v1 = b1 - dt*u01, v2 = b2 - dt*u02;
    float n1 = sqrtf(v0*v0 + v1*v1 + v2*v2);
    float i1 = 1.f / (n1 + 1e-8f);
    float u10 = v0*i1, u11 = v1*i1, u12 = v2*i1;
    float u20 = u01*u12 - u02*u11;
    float u21 = u02*u10 - u00*u12;
    float u22 = u00*u11 - u01*u10;
    float um = useful[t], om = 1.f - um;
    float R00 = um*u00 + om, R01 = um*u10,      R02 = um*u20;
    float R10 = um*u01,      R11 = um*u11 + om, R12 = um*u21;
    float R20 = um*u02,      R21 = um*u12,      R22 = um*u22 + om;
    float* o = out + (size_t)bq*OUTW + 19 + t*9;
    o[0] = R00*m; o[1] = R01*m; o[2] = R02*m;
    o[3] = R10*m; o[4] = R11*m; o[5] = R12*m;
    o[6] = R20*m; o[7] = R21*m; o[8] = R22*m;
  }
}

extern "C" void kernel_launch(void* const* d_in, const int* in_sizes, int n_in,
                              void* d_out, int out_size, void* d_ws, size_t ws_size,
                              hipStream_t stream)
{
  const float* feat   = (const float*)d_in[0];
  const float* scores = (const float*)d_in[1];
  const float* K_cam  = (const float*)d_in[2];
  const float* pos_emb= (const float*)d_in[3];
  const float* Wtok   = (const float*)d_in[4];
  const float* btok   = (const float*)d_in[5];
  const float* Wq     = (const float*)d_in[6];
  const float* Wk     = (const float*)d_in[7];
  const float* Wv     = (const float*)d_in[8];
  const float* Wo     = (const float*)d_in[9];
  const float* g1     = (const float*)d_in[10];
  const float* b1n    = (const float*)d_in[11];
  const float* W1     = (const float*)d_in[12];
  const float* bf1    = (const float*)d_in[13];
  const float* W2     = (const float*)d_in[14];
  const float* bf2    = (const float*)d_in[15];
  const float* g2     = (const float*)d_in[16];
  const float* b2n    = (const float*)d_in[17];
  const float* offW1  = (const float*)d_in[18];
  const float* offb1  = (const float*)d_in[19];
  const float* offW2  = (const float*)d_in[20];
  const float* offb2  = (const float*)d_in[21];
  const float* dW1    = (const float*)d_in[22];
  const float* db1    = (const float*)d_in[23];
  const float* dW2    = (const float*)d_in[24];
  const float* db2    = (const float*)d_in[25];
  const float* sW1    = (const float*)d_in[26];
  const float* sb1    = (const float*)d_in[27];
  const float* sW2    = (const float*)d_in[28];
  const float* sb2    = (const float*)d_in[29];
  const float* pW1    = (const float*)d_in[30];
  const float* pb1    = (const float*)d_in[31];
  const float* pW2    = (const float*)d_in[32];
  const float* pb2    = (const float*)d_in[33];
  const float* ibp    = (const float*)d_in[34];
  const float* useful = (const float*)d_in[35];
  float* out = (float*)d_out;

  char* wsp = (char*)d_ws;
  size_t off = 0;
  auto alloc = [&](size_t bytes)->char*{
    char* p = wsp + off;
    off += (bytes + 255) & ~((size_t)255);
    return p;
  };
  int*   t_idx  = (int*)  alloc(BKQ*4);
  float* t_mask = (float*)alloc(BKQ*4);
  float* t_col  = (float*)alloc(BKQ*4);
  float* t_row  = (float*)alloc(BKQ*4);
  u16*   feat_bf= (u16*)  alloc((size_t)BB*TOK*CE*2);
  u16*   wtokT  = (u16*)  alloc((size_t)DD*CE*2);
  u16*   ctx_bf = (u16*)  alloc((size_t)BB*TOK*DD*2);
  u16*   ctxT_bf= (u16*)  alloc((size_t)BB*TOK*DD*2);
  u16*   wqT    = (u16*)  alloc((size_t)LL*DD*DD*2);
  u16*   woT    = (u16*)  alloc((size_t)LL*DD*DD*2);
  u16*   w1T    = (u16*)  alloc((size_t)LL*DD*MM*2);
  u16*   w2T    = (u16*)  alloc((size_t)LL*MM*DD*2);
  u16*   headsT = (u16*)  alloc((size_t)4*DD*DD*2);
  u16*   pw2T   = (u16*)  alloc((size_t)1024*DD*2);
  float* x      = (float*)alloc((size_t)BKQ*DD*4);
  u16*   x_bf   = (u16*)  alloc((size_t)BKQ*DD*2);
  float* u      = (float*)alloc((size_t)BKQ*DD*4);
  u16*   z_bf   = (u16*)  alloc((size_t)BKQ*HH*DD*2);
  u16*   logits = (u16*)  alloc((size_t)BB*QH*TOK*2);
  u16*   att_bf = (u16*)  alloc((size_t)BB*QH*TOK*2);
  float* parts  = (float*)alloc((size_t)BB*8*QH*DD*4);
  u16*   o_pre  = (u16*)  alloc((size_t)BKQ*DD*2);
  u16*   mid_bf = (u16*)  alloc((size_t)BKQ*MM*2);
  float* h4     = (float*)alloc((size_t)BKQ*2048*4);
  u16*   hp_bf  = (u16*)  alloc((size_t)BKQ*DD*2);
  float* hb4    = (float*)alloc(2048*4);
  float* cvec2  = (float*)alloc(1024*4);
  float* rot6d  = (float*)alloc((size_t)BKQ*NROT*4);
  if (off > ws_size) return;

  const float scale = 0.17677669529663687f; // 1/sqrt(32)

  // job table for unified weight transposer (22 jobs; Wq/Wo via k_tconvL)
  PJobs J;
  int ntl = 0, nj = 0;
  auto addjob = [&](const float* s, u16* d, int R, int C){
    J.s[nj] = s; J.d[nj] = d; J.R[nj] = R; J.C[nj] = C; J.t0[nj] = ntl;
    ntl += ((R+31)/32) * ((C+31)/32);
    nj++;
  };
  addjob(Wtok, wtokT, CE, DD);
  for (int l = 0; l < LL; l++) addjob(W1 + (size_t)l*DD*MM, w1T + (size_t)l*MM*DD, DD, MM);
  for (int l = 0; l < LL; l++) addjob(W2 + (size_t)l*MM*DD, w2T + (size_t)l*DD*MM, MM, DD);
  addjob(offW1, headsT,            DD, DD);
  addjob(dW1,   headsT + DD*DD,    DD, DD);
  addjob(sW1,   headsT + 2*DD*DD,  DD, DD);
  addjob(pW1,   headsT + 3*DD*DD,  DD, DD);
  addjob(pW2,   pw2T, DD, NROT);
  J.t0[nj] = ntl; J.njobs = nj; J.ntiles = ntl;

  k_nms_topk<<<BB, 256, 0, stream>>>(scores, t_idx, t_mask, t_col, t_row);
  k_cvt_bf16<<<3072, 256, 0, stream>>>(feat, feat_bf, BB*TOK*CE/4);
  k_prepw<<<2048, 256, 0, stream>>>(J);
  k_tconvL<<<dim3(16,16,LL), 256, 0, stream>>>(Wq, wqT, DD, DD);
  k_tconvL<<<dim3(16,16,LL), 256, 0, stream>>>(Wo, woT, DD, DD);
  k_gemm_emb<<<dim3(DD/128, (BB*TOK)/128, 1), 256, 0, stream>>>(feat_bf, wtokT, ctx_bf, btok, pos_emb);
  k_transp_b<<<dim3(DD/32, TOK/32, BB), 256, 0, stream>>>(ctx_bf, ctxT_bf, TOK, DD);
  k_misc<<<193, 256, 0, stream>>>(feat, Wtok, btok, pos_emb, t_idx, x, pW1, pb1, ibp, hb4,
                                  offb1, db1, sb1, pb2, cvec2);

  for (int l = 0; l < LL; l++){
    // u = LN1(x) @ Wq * scale   (LN fused in-block)
    k_mf64<0,0,0,1,0,0><<<dim3(8,1), 256, 0, stream>>>(
        nullptr, x, g1 + l*DD, b1n + l*DD, wqT + (size_t)l*DD*DD, nullptr,
        u, nullptr, nullptr, DD, DD, DD, DD, scale);
    k_zker<<<dim3(4,HH), 256, 0, stream>>>(u, Wk + (size_t)l*DD*DD, z_bf);
    // logits[b] = Z_b (256x512) @ ctx_b^T -> bf16
    k_gemm_bt64<1><<<dim3(TOK/64, 2, BB), 256, 0, stream>>>(
        z_bf, ctx_bf, nullptr, logits,
        DD, DD, DD, TOK, (long)QH*DD, (long)TOK*DD, (long)QH*TOK, 1);
    k_softmax<<<BB*QH, 256, 0, stream>>>(logits, att_bf);
    // parts[b*8+ks] = att_b @ ctxT_b^T over K-slice ks
    k_gemm_bt64<0><<<dim3(DD/64, 2, BB*8), 256, 0, stream>>>(
        att_bf, ctxT_bf, parts, nullptr,
        TOK/8, TOK, TOK, DD, (long)QH*TOK, (long)DD*TOK, (long)QH*DD, 8);
    k_ovp<<<dim3(4,HH), 256, 0, stream>>>(parts, Wv + (size_t)l*DD*DD, o_pre);
    // x += o_pre @ Wo   (ksplit=8, atomic; 1 K-step per block)
    k_mf64<0,1,0,0,0,0><<<dim3(8,8), 256, 0, stream>>>(
        o_pre, nullptr, nullptr, nullptr, woT + (size_t)l*DD*DD, nullptr,
        x, nullptr, nullptr, DD, DD, DD/8, DD, 1.f);
    // mid = gelu(LN2(x) @ W1 + bf1)  -> bf16
    k_mf64<2,0,1,1,0,0><<<dim3(MM/64,1), 256, 0, stream>>>(
        nullptr, x, g2 + l*DD, b2n + l*DD, w1T + (size_t)l*DD*MM, bf1 + l*MM,
        nullptr, mid_bf, nullptr, MM, DD, DD, MM, 1.f);
    // x += mid @ W2 + bf2  (ksplit=8, atomic; 4 K-steps per block)
    k_mf64<0,1,0,0,0,0><<<dim3(8,8), 256, 0, stream>>>(
        mid_bf, nullptr, nullptr, nullptr, w2T + (size_t)l*MM*DD, bf2 + l*DD,
        x, nullptr, nullptr, DD, MM, MM/8, DD, 1.f);
  }

  // heads: h4 = relu(x @ [offW1|dW1|sW1|pW1] + hb4), with bf16 copy of the pose slice
  k_cvt_bf16<<<32, 256, 0, stream>>>(x, x_bf, BKQ*DD/4);
  k_mf64<1,0,0,0,0,1><<<dim3(32,1), 256, 0, stream>>>(
      x_bf, nullptr, nullptr, nullptr, headsT, hb4,
      h4, nullptr, hp_bf, 2048, DD, DD, 2048, 1.f);
  // rot6d = h_p @ pW2 + (pb2 + ibp)
  k_mf64<0,0,0,0,1,0><<<dim3(16,1), 256, 0, stream>>>(
      hp_bf, nullptr, nullptr, nullptr, pw2T, cvec2,
      rot6d, nullptr, nullptr, NROT, DD, DD, NROT, 1.f);
  k_final<<<BKQ, 256, 0, stream>>>(h4, rot6d, offW2, offb2, dW2, db2, sW2, sb2,
                                   K_cam, useful, t_mask, t_col, t_row, out);
}

// Round 8
// 964.597 us; speedup vs baseline: 4.4765x; 1.3039x over previous
//
#include <hip/hip_runtime.h>

typedef unsigned int uint;
typedef unsigned short u16;

#define BB 4
#define CE 384
#define DD 512
#define LL 8
#define HH 16
#define MM 2048
#define NJ 163
#define TOK 4096
#define BKQ 64
#define QH 256
#define OUTW 1486
#define NROT 978
#define QKSCALE 0.17677669529663687f

typedef __attribute__((ext_vector_type(8))) short short8;
typedef __attribute__((ext_vector_type(4))) float float4v;

static __device__ __forceinline__ u16 f2bf(float f){
  union { float f; uint u; } c; c.f = f;
  uint u = c.u;
  return (u16)((u + 0x7FFFu + ((u >> 16) & 1u)) >> 16);
}
static __device__ __forceinline__ float bf2f(u16 u){
  union { uint u; float f; } c; c.u = ((uint)u) << 16;
  return c.f;
}
static __device__ __forceinline__ float wred_sum(float v){
  for (int o = 32; o; o >>= 1) v += __shfl_xor(v, o, 64);
  return v;
}
static __device__ __forceinline__ void gl16(const void* g, void* l){
  __builtin_amdgcn_global_load_lds((const __attribute__((address_space(1))) void*)g,
                                   (__attribute__((address_space(3))) void*)l, 16, 0, 0);
}

// ---------------- NMS + top-k (register scan, exact fp32, stable ties) ----------------
__global__ __launch_bounds__(256) void k_nms_topk(const float* __restrict__ scores,
    int* __restrict__ oidx, float* __restrict__ omask, float* __restrict__ ocol, float* __restrict__ orow)
{
  int b = blockIdx.x, t = threadIdx.x;
  __shared__ float sraw[4096];
  __shared__ float sv[4]; __shared__ int si[4]; __shared__ int swin;
  const float* sp = scores + (size_t)b * 4096;
  for (int i = t; i < 4096; i += 256) sraw[i] = sp[i];
  __syncthreads();
  float v[16];
  #pragma unroll
  for (int j = 0; j < 16; j++){
    int i = t + j*256;
    int r = i >> 6, c = i & 63;
    float mx = -1e30f;
    for (int dr = -1; dr <= 1; dr++){
      int rr = r + dr; if (rr < 0 || rr > 63) continue;
      for (int dc = -1; dc <= 1; dc++){
        int cc = c + dc; if (cc < 0 || cc > 63) continue;
        mx = fmaxf(mx, sraw[rr*64+cc]);
      }
    }
    float s = sraw[i];
    v[j] = (s == mx) ? s : 0.0f;
  }
  int lane = t & 63, wv = t >> 6;
  for (int iter = 0; iter < 16; iter++){
    float best = -1e30f; int bi_ = 1 << 30;
    #pragma unroll
    for (int j = 0; j < 16; j++){
      if (v[j] > best){ best = v[j]; bi_ = t + j*256; }
    }
    #pragma unroll
    for (int o = 32; o; o >>= 1){
      float ov = __shfl_xor(best, o, 64);
      int oi = __shfl_xor(bi_, o, 64);
      if (ov > best || (ov == best && oi < bi_)){ best = ov; bi_ = oi; }
    }
    if (lane == 0){ sv[wv] = best; si[wv] = bi_; }
    __syncthreads();
    if (t == 0){
      float bb = sv[0]; int ii = si[0];
      for (int k = 1; k < 4; k++){
        if (sv[k] > bb || (sv[k] == bb && si[k] < ii)){ bb = sv[k]; ii = si[k]; }
      }
      oidx[b*16+iter] = ii;
      omask[b*16+iter] = (bb >= 0.3f) ? 1.f : 0.f;
      ocol[b*16+iter] = (float)(ii & 63);
      orow[b*16+iter] = (float)(ii >> 6);
      swin = ii;
    }
    __syncthreads();
    int wi = swin;
    if ((wi & 255) == t) v[wi >> 8] = -1e30f;
    __syncthreads();
  }
}

// ---------------- fp32 -> bf16 convert ----------------
__global__ __launch_bounds__(256) void k_cvt_bf16(const float* __restrict__ in, u16* __restrict__ out, int n4){
  int i = blockIdx.x*256 + threadIdx.x;
  int stride = gridDim.x*256;
  for (int j = i; j < n4; j += stride){
    float4 v = ((const float4*)in)[j];
    ushort4 o;
    o.x = f2bf(v.x); o.y = f2bf(v.y); o.z = f2bf(v.z); o.w = f2bf(v.w);
    ((ushort4*)out)[j] = o;
  }
}

// ---------------- unified transpose+convert: up to 24 jobs fp32(R,C)->bf16(C,R) ----------------
struct PJobs {
  const float* s[24]; u16* d[24];
  int R[24], C[24], t0[25];
  int njobs, ntiles;
};
__global__ __launch_bounds__(256) void k_prepw(PJobs J){
  __shared__ float tile[32][33];
  for (int g = blockIdx.x; g < J.ntiles; g += gridDim.x){
    int j = 0;
    while (g >= J.t0[j+1]) j++;
    int ti = g - J.t0[j];
    int C_ = J.C[j], R_ = J.R[j];
    int tC = (C_ + 31) >> 5;
    int ry = ti / tC, cx = ti - ry*tC;
    int c0 = cx*32, r0 = ry*32;
    int tx = threadIdx.x & 31, ty = threadIdx.x >> 5;
    const float* src = J.s[j]; u16* dst = J.d[j];
    for (int i = 0; i < 32; i += 8){
      float v = 0.f;
      if (c0+tx < C_) v = src[(size_t)(r0+ty+i)*C_ + c0+tx];
      tile[ty+i][tx] = v;
    }
    __syncthreads();
    for (int i = 0; i < 32; i += 8){
      if (c0+ty+i < C_) dst[(size_t)(c0+ty+i)*R_ + r0+tx] = f2bf(tile[tx][ty+i]);
    }
    __syncthreads();
  }
}

// ---------------- bf16 transpose (R,C) -> (C,R), batched in z ----------------
__global__ __launch_bounds__(256) void k_transp_b(const u16* __restrict__ in, u16* __restrict__ out, int R, int C){
  in  += (size_t)blockIdx.z * R * C;
  out += (size_t)blockIdx.z * R * C;
  __shared__ u16 tile[32][33];
  int c0 = blockIdx.x*32, r0 = blockIdx.y*32;
  int tx = threadIdx.x & 31, ty = threadIdx.x >> 5;
  for (int i = 0; i < 32; i += 8) tile[ty+i][tx] = in[(size_t)(r0+ty+i)*C + c0+tx];
  __syncthreads();
  for (int i = 0; i < 32; i += 8) out[(size_t)(c0+ty+i)*R + r0+tx] = tile[tx][ty+i];
}

// ---------------- AT prep: AT[(h*512+dout)][din] = QKSCALE * sum_dh Wq[din][h*32+dh]*Wk[dout][h*32+dh] ----------------
__global__ __launch_bounds__(256) void k_wqk(const float* __restrict__ wq, const float* __restrict__ wk,
    u16* __restrict__ AT)
{
  __shared__ __align__(16) u16 As[2560];
  __shared__ __align__(16) u16 Bs[2560];
  int id = blockIdx.x, t = threadIdx.x;
  int rt = id & 127, dt = id >> 7;
  int h = rt >> 3, dout0 = (rt & 7)*64, din0 = dt*64;
  int r = t >> 2, c0 = (t & 3)*8;
  {
    float4 u0 = *(const float4*)(wk + (size_t)(dout0+r)*DD + h*32 + c0);
    float4 u1 = *(const float4*)(wk + (size_t)(dout0+r)*DD + h*32 + c0 + 4);
    u16* d = As + r*40 + c0;
    d[0]=f2bf(u0.x); d[1]=f2bf(u0.y); d[2]=f2bf(u0.z); d[3]=f2bf(u0.w);
    d[4]=f2bf(u1.x); d[5]=f2bf(u1.y); d[6]=f2bf(u1.z); d[7]=f2bf(u1.w);
    float4 v0 = *(const float4*)(wq + (size_t)(din0+r)*DD + h*32 + c0);
    float4 v1 = *(const float4*)(wq + (size_t)(din0+r)*DD + h*32 + c0 + 4);
    u16* e = Bs + r*40 + c0;
    e[0]=f2bf(v0.x); e[1]=f2bf(v0.y); e[2]=f2bf(v0.z); e[3]=f2bf(v0.w);
    e[4]=f2bf(v1.x); e[5]=f2bf(v1.y); e[6]=f2bf(v1.z); e[7]=f2bf(v1.w);
  }
  __syncthreads();
  int lane = t & 63, w = t >> 6, lr = lane & 15, lk = lane >> 4;
  short8 af = *(const short8*)&As[(w*16+lr)*40 + lk*8];
  float4v acc[4];
  float4v z4 = {0.f,0.f,0.f,0.f};
  acc[0]=z4; acc[1]=z4; acc[2]=z4; acc[3]=z4;
  #pragma unroll
  for (int nf = 0; nf < 4; nf++){
    short8 bf8 = *(const short8*)&Bs[(nf*16+lr)*40 + lk*8];
    acc[nf] = __builtin_amdgcn_mfma_f32_16x16x32_bf16(af, bf8, acc[nf], 0, 0, 0);
  }
  #pragma unroll
  for (int nf = 0; nf < 4; nf++){
    #pragma unroll
    for (int jj = 0; jj < 4; jj++){
      int row = w*16 + lk*4 + jj;
      AT[(size_t)(h*512 + dout0 + row)*DD + din0 + nf*16 + lr] = f2bf(acc[nf][jj]*QKSCALE);
    }
  }
}

// ---------------- WVO prep: WVOT[dout][(h*512+Dc)] = sum_c Wv[Dc][h*32+c]*Wo[h*32+c][dout] ----------------
__global__ __launch_bounds__(256) void k_wvo(const float* __restrict__ wv, const float* __restrict__ wo,
    u16* __restrict__ WVOT)
{
  __shared__ __align__(16) u16 As[2560];
  __shared__ __align__(16) u16 Bs[2560];
  int id = blockIdx.x, t = threadIdx.x;
  int ct = id & 127, dt = id >> 7;
  int h = ct >> 3, Dc0 = (ct & 7)*64, dout0 = dt*64;
  {
    int c = t >> 3, d8 = (t & 7)*8;
    float4 a0 = *(const float4*)(wo + (size_t)(h*32+c)*DD + dout0 + d8);
    float4 a1 = *(const float4*)(wo + (size_t)(h*32+c)*DD + dout0 + d8 + 4);
    As[(d8+0)*40 + c] = f2bf(a0.x);
    As[(d8+1)*40 + c] = f2bf(a0.y);
    As[(d8+2)*40 + c] = f2bf(a0.z);
    As[(d8+3)*40 + c] = f2bf(a0.w);
    As[(d8+4)*40 + c] = f2bf(a1.x);
    As[(d8+5)*40 + c] = f2bf(a1.y);
    As[(d8+6)*40 + c] = f2bf(a1.z);
    As[(d8+7)*40 + c] = f2bf(a1.w);
    int r = t >> 2, c0 = (t & 3)*8;
    float4 v0 = *(const float4*)(wv + (size_t)(Dc0+r)*DD + h*32 + c0);
    float4 v1 = *(const float4*)(wv + (size_t)(Dc0+r)*DD + h*32 + c0 + 4);
    u16* e = Bs + r*40 + c0;
    e[0]=f2bf(v0.x); e[1]=f2bf(v0.y); e[2]=f2bf(v0.z); e[3]=f2bf(v0.w);
    e[4]=f2bf(v1.x); e[5]=f2bf(v1.y); e[6]=f2bf(v1.z); e[7]=f2bf(v1.w);
  }
  __syncthreads();
  int lane = t & 63, w = t >> 6, lr = lane & 15, lk = lane >> 4;
  short8 af = *(const short8*)&As[(w*16+lr)*40 + lk*8];
  float4v acc[4];
  float4v z4 = {0.f,0.f,0.f,0.f};
  acc[0]=z4; acc[1]=z4; acc[2]=z4; acc[3]=z4;
  #pragma unroll
  for (int nf = 0; nf < 4; nf++){
    short8 bf8 = *(const short8*)&Bs[(nf*16+lr)*40 + lk*8];
    acc[nf] = __builtin_amdgcn_mfma_f32_16x16x32_bf16(af, bf8, acc[nf], 0, 0, 0);
  }
  #pragma unroll
  for (int nf = 0; nf < 4; nf++){
    #pragma unroll
    for (int jj = 0; jj < 4; jj++){
      int row = w*16 + lk*4 + jj;
      WVOT[(size_t)(dout0 + row)*8192 + h*512 + Dc0 + nf*16 + lr] = f2bf(acc[nf][jj]);
    }
  }
}

// ---------------- reduce 8 PV split-K partials -> c_flat bf16 [bq][h*512+Dc] ----------------
__global__ __launch_bounds__(256) void k_red8(const float* __restrict__ parts, u16* __restrict__ cf){
  int i4 = blockIdx.x*256 + threadIdx.x;   // 131072 float4 groups
  int elem = i4*4;
  int row = elem >> 13, col = elem & 8191;
  int b = row >> 4, q = row & 15, h = col >> 9, Dc = col & 511;
  const float* src = parts + ((size_t)b*8)*131072 + (size_t)(q*16+h)*512 + Dc;
  float4 s = *(const float4*)src;
  #pragma unroll
  for (int ks = 1; ks < 8; ks++){
    float4 g = *(const float4*)(src + (size_t)ks*131072);
    s.x += g.x; s.y += g.y; s.z += g.z; s.w += g.w;
  }
  ushort4 o;
  o.x = f2bf(s.x); o.y = f2bf(s.y); o.z = f2bf(s.z); o.w = f2bf(s.w);
  *(ushort4*)&cf[(size_t)row*8192 + col] = o;
}

// ---------------- ctx embed GEMM: ctx = feat_bf @ wtokT^T + btok + pos_emb -> bf16 ----------------
__global__ __launch_bounds__(256) void k_gemm_emb(
    const u16* __restrict__ A, const u16* __restrict__ Bt, u16* __restrict__ Cb,
    const float* __restrict__ ep1, const float* __restrict__ ep2)
{
  int m0 = blockIdx.y*128, n0 = blockIdx.x*128;
  __shared__ __align__(16) u16 As[128*64];
  __shared__ __align__(16) u16 Bs[128*64];
  int t = threadIdx.x, lane = t & 63, wave = t >> 6;
  int wr = wave >> 1, wc = wave & 1;
  int lr = lane & 15, lk = lane >> 4;
  int sr8 = t >> 3, sl = t & 7;
  int sw = ((sl ^ (sr8 & 7)) * 8);
  float4v acc[4][4];
  float4v z4 = {0.f, 0.f, 0.f, 0.f};
  #pragma unroll
  for (int i = 0; i < 4; i++)
    #pragma unroll
    for (int j = 0; j < 4; j++) acc[i][j] = z4;
  for (int kt = 0; kt < CE; kt += 64){
    __syncthreads();
    #pragma unroll
    for (int rg = 0; rg < 4; rg++){
      gl16(A + (size_t)(m0 + rg*32 + sr8)*CE + kt + sw, As + rg*2048 + 8*t);
      gl16(Bt + (size_t)(n0 + rg*32 + sr8)*CE + kt + sw, Bs + rg*2048 + 8*t);
    }
    __syncthreads();
    #pragma unroll
    for (int s = 0; s < 2; s++){
      int slot = ((s*4 + lk) ^ (lr & 7)) * 8;
      short8 af[4], bfr[4];
      #pragma unroll
      for (int i = 0; i < 4; i++) af[i] = *(const short8*)&As[(wr*64 + i*16 + lr)*64 + slot];
      #pragma unroll
      for (int j = 0; j < 4; j++) bfr[j] = *(const short8*)&Bs[(wc*64 + j*16 + lr)*64 + slot];
      #pragma unroll
      for (int i = 0; i < 4; i++)
        #pragma unroll
        for (int j = 0; j < 4; j++)
          acc[i][j] = __builtin_amdgcn_mfma_f32_16x16x32_bf16(af[i], bfr[j], acc[i][j], 0, 0, 0);
    }
  }
  #pragma unroll
  for (int i = 0; i < 4; i++){
    int rbase = m0 + wr*64 + i*16 + lk*4;
    #pragma unroll
    for (int j = 0; j < 4; j++){
      int cc = n0 + wc*64 + j*16 + lr;
      #pragma unroll
      for (int jj = 0; jj < 4; jj++){
        int rr = rbase + jj;
        float vv = acc[i][j][jj] + ep1[cc] + ep2[(size_t)(rr & 4095)*DD + cc];
        Cb[(size_t)rr*DD + cc] = f2bf(vv);
      }
    }
  }
}

// ---------------- misc: gather + pose-const + bias packing ----------------
__global__ __launch_bounds__(256) void k_misc(const float* __restrict__ feat, const float* __restrict__ Wtok,
    const float* __restrict__ btok, const float* __restrict__ pos_emb, const int* __restrict__ oidx,
    float* __restrict__ x, const float* __restrict__ pW1, const float* __restrict__ pb1,
    const float* __restrict__ ibp, float* __restrict__ hb4,
    const float* __restrict__ offb1, const float* __restrict__ db1, const float* __restrict__ sb1,
    const float* __restrict__ pb2, float* __restrict__ cvec2)
{
  int bid = blockIdx.x, t = threadIdx.x;
  if (bid < 64){
    int b = bid >> 4, tok = oidx[bid];
    __shared__ float fs[CE];
    const float* fr = feat + ((size_t)b*TOK + tok) * CE;
    for (int i = t; i < CE; i += 256) fs[i] = fr[i];
    __syncthreads();
    for (int d = t; d < DD; d += 256){
      float acc = btok[d] + pos_emb[(size_t)tok*DD + d];
      for (int i = 0; i < CE; i++) acc += fs[i] * Wtok[(size_t)i*DD + d];
      x[(size_t)bid*DD + d] = acc;
    }
  } else if (bid < 192){
    int d = (bid - 64)*4 + (t >> 6);
    int ln = t & 63;
    float acc = 0.f;
    for (int i = ln; i < NJ*6; i += 64) acc += ibp[i] * pW1[(size_t)(DD+i)*DD + d];
    acc = wred_sum(acc);
    if (ln == 0) hb4[1536 + d] = acc + pb1[d];
  } else {
    for (int i = t; i < 1536; i += 256)
      hb4[i] = (i < 512) ? offb1[i] : (i < 1024 ? db1[i-512] : sb1[i-1024]);
    for (int i = t; i < 1024; i += 256)
      cvec2[i] = (i < NJ*6) ? (pb2[i] + ibp[i]) : 0.f;
  }
}

// ---------------- MFMA GEMM, 128(M) x 64(N) tiles: C = A(MxK) @ Bt(NxK)^T ----------------
// EPI 0: fp32 store into slice bz (split-K partials).  EPI 1: bf16 store into batch slice.
template<int EPI>
__global__ __launch_bounds__(256) void k_gemm_bt64(
    const u16* __restrict__ A, const u16* __restrict__ Bt,
    float* __restrict__ C, u16* __restrict__ Cb,
    int Kslice, int lda, int ldb, int ldc,
    long sA, long sB, long sC, int ksplit)
{
  int bz = blockIdx.z;
  int batch = bz / ksplit, ks = bz - batch*ksplit;
  const u16* Ab = A + (size_t)batch*sA + (size_t)ks*Kslice;
  const u16* Bb = Bt + (size_t)batch*sB + (size_t)ks*Kslice;
  int m0 = blockIdx.y*128, n0 = blockIdx.x*64;
  __shared__ __align__(16) u16 As[128*64];
  __shared__ __align__(16) u16 Bs[64*64];
  int t = threadIdx.x, lane = t & 63, w = t >> 6;
  int lr = lane & 15, lk = lane >> 4;
  int sr8 = t >> 3, sl = t & 7;
  int sw = ((sl ^ (sr8 & 7)) * 8);
  float4v acc[2][4];
  float4v z4 = {0.f,0.f,0.f,0.f};
  #pragma unroll
  for (int i = 0; i < 2; i++)
    #pragma unroll
    for (int j = 0; j < 4; j++) acc[i][j] = z4;

  for (int kt = 0; kt < Kslice; kt += 64){
    __syncthreads();
    #pragma unroll
    for (int rg = 0; rg < 4; rg++)
      gl16(Ab + (size_t)(m0 + rg*32 + sr8)*lda + kt + sw, As + rg*2048 + 8*t);
    #pragma unroll
    for (int rg = 0; rg < 2; rg++)
      gl16(Bb + (size_t)(n0 + rg*32 + sr8)*ldb + kt + sw, Bs + rg*2048 + 8*t);
    __syncthreads();
    #pragma unroll
    for (int s = 0; s < 2; s++){
      int slot = ((s*4 + lk) ^ (lr & 7)) * 8;
      short8 af[2], bfr[4];
      #pragma unroll
      for (int i = 0; i < 2; i++) af[i] = *(const short8*)&As[(w*32 + i*16 + lr)*64 + slot];
      #pragma unroll
      for (int j = 0; j < 4; j++) bfr[j] = *(const short8*)&Bs[(j*16 + lr)*64 + slot];
      #pragma unroll
      for (int i = 0; i < 2; i++)
        #pragma unroll
        for (int j = 0; j < 4; j++)
          acc[i][j] = __builtin_amdgcn_mfma_f32_16x16x32_bf16(af[i], bfr[j], acc[i][j], 0, 0, 0);
    }
  }
  #pragma unroll
  for (int i = 0; i < 2; i++){
    int rbase = m0 + w*32 + i*16 + lk*4;
    #pragma unroll
    for (int j = 0; j < 4; j++){
      int cc = n0 + j*16 + lr;
      #pragma unroll
      for (int jj = 0; jj < 4; jj++){
        int rr = rbase + jj;
        if (EPI == 0) C[(size_t)bz*sC + (size_t)rr*ldc + cc] = acc[i][j][jj];
        else Cb[(size_t)batch*sC + (size_t)rr*ldc + cc] = f2bf(acc[i][j][jj]);
      }
    }
  }
}

// ---------------- skinny MFMA GEMM: C(64 x N) = A(64 x K) @ Bt(N x K)^T ----------------
// ACT: 0 none, 1 relu, 2 gelu.  RES: 0 store, 1 atomicAdd.  OUTB: bf16 out.
// DOLN: A = LN(xf)*g+b in-block.  NG: guard col<N.  HPB: bf16 copy of cols>=1536.
// ZMAP: store bf16 into z layout [b][q*16+h][dout] (col = h*512+dout).
template<int ACT, int RES, int OUTB, int DOLN, int NG, int HPB, int ZMAP = 0>
__global__ __launch_bounds__(256) void k_mf64(
    const u16* __restrict__ A, const float* __restrict__ xf,
    const float* __restrict__ g, const float* __restrict__ bb,
    const u16* __restrict__ Bt, const float* __restrict__ bias,
    float* __restrict__ C, u16* __restrict__ Cb, u16* __restrict__ Cb2,
    int N, int K, int kper, int ldc, float alpha)
{
  __shared__ __align__(16) u16 Asl[DOLN ? 64*520 : 64*64];
  __shared__ __align__(16) u16 Bs[64*64];
  int t = threadIdx.x, lane = t & 63, w = t >> 6;
  int lr = lane & 15, lk = lane >> 4;
  int n0 = blockIdx.x*64;
  int ks = blockIdx.y, kbeg = ks*kper;
  int sr8 = t >> 3, sl = t & 7;
  int sw = ((sl ^ (sr8 & 7)) * 8);

  if (DOLN){
    for (int rr = 0; rr < 16; rr++){
      int row = w*16 + rr;
      const float* xr = xf + (size_t)row*DD;
      float4 v0 = *(const float4*)(xr + lane*4);
      float4 v1 = *(const float4*)(xr + 256 + lane*4);
      float s = v0.x+v0.y+v0.z+v0.w + v1.x+v1.y+v1.z+v1.w;
      s = wred_sum(s);
      float mu = s * (1.f/DD);
      float d0=v0.x-mu, d1=v0.y-mu, d2=v0.z-mu, d3=v0.w-mu;
      float e0=v1.x-mu, e1=v1.y-mu, e2=v1.z-mu, e3=v1.w-mu;
      float q = d0*d0+d1*d1+d2*d2+d3*d3 + e0*e0+e1*e1+e2*e2+e3*e3;
      q = wred_sum(q);
      float inv = rsqrtf(q * (1.f/DD) + 1e-5f);
      float4 g0 = *(const float4*)(g + lane*4);
      float4 g1 = *(const float4*)(g + 256 + lane*4);
      float4 b0 = *(const float4*)(bb + lane*4);
      float4 b1 = *(const float4*)(bb + 256 + lane*4);
      u16* dst = &Asl[row*520];
      dst[lane*4+0] = f2bf(d0*inv*g0.x + b0.x);
      dst[lane*4+1] = f2bf(d1*inv*g0.y + b0.y);
      dst[lane*4+2] = f2bf(d2*inv*g0.z + b0.z);
      dst[lane*4+3] = f2bf(d3*inv*g0.w + b0.w);
      dst[256+lane*4+0] = f2bf(e0*inv*g1.x + b1.x);
      dst[256+lane*4+1] = f2bf(e1*inv*g1.y + b1.y);
      dst[256+lane*4+2] = f2bf(e2*inv*g1.z + b1.z);
      dst[256+lane*4+3] = f2bf(e3*inv*g1.w + b1.w);
    }
  }

  float4v acc[4];
  float4v z4 = {0.f,0.f,0.f,0.f};
  acc[0]=z4; acc[1]=z4; acc[2]=z4; acc[3]=z4;

  for (int kc = kbeg; kc < kbeg + kper; kc += 64){
    __syncthreads();
    if (!DOLN){
      gl16(A + (size_t)sr8*K + kc + sw,        (u16*)Asl + 8*t);
      gl16(A + (size_t)(32+sr8)*K + kc + sw,   (u16*)Asl + 2048 + 8*t);
    }
    gl16(Bt + (size_t)(n0+sr8)*K + kc + sw,      (u16*)Bs + 8*t);
    gl16(Bt + (size_t)(n0+32+sr8)*K + kc + sw,   (u16*)Bs + 2048 + 8*t);
    __syncthreads();
    #pragma unroll
    for (int s = 0; s < 2; s++){
      int slot = ((s*4 + lk) ^ (lr & 7)) * 8;
      short8 af;
      if (DOLN) af = *(const short8*)&Asl[(w*16+lr)*520 + kc + s*32 + lk*8];
      else      af = *(const short8*)&Asl[(w*16+lr)*64 + slot];
      #pragma unroll
      for (int nf = 0; nf < 4; nf++){
        short8 bf8 = *(const short8*)&Bs[(nf*16+lr)*64 + slot];
        acc[nf] = __builtin_amdgcn_mfma_f32_16x16x32_bf16(af, bf8, acc[nf], 0, 0, 0);
      }
    }
  }
  #pragma unroll
  for (int nf = 0; nf < 4; nf++){
    int col = n0 + nf*16 + lr;
    float bsv = (bias && ks == 0) ? bias[col] : 0.f;
    #pragma unroll
    for (int jj = 0; jj < 4; jj++){
      int row = w*16 + lk*4 + jj;
      float v = acc[nf][jj]*alpha + bsv;
      if (ACT == 1) v = fmaxf(v, 0.f);
      else if (ACT == 2) v = 0.5f*v*(1.f + tanhf(0.7978845608028654f*(v + 0.044715f*v*v*v)));
      if (NG && col >= N) continue;
      if (ZMAP){
        int b_ = row >> 4, q_ = row & 15, h_ = col >> 9, d_ = col & 511;
        Cb[((size_t)b_*QH + (q_ << 4) + h_)*DD + d_] = f2bf(v);
        continue;
      }
      size_t o = (size_t)row*ldc + col;
      if (OUTB == 1) Cb[o] = f2bf(v);
      else if (RES == 0) C[o] = v;
      else atomicAdd(&C[o], v);
      if (HPB && col >= 1536) Cb2[(size_t)row*DD + (col - 1536)] = f2bf(v);
    }
  }
}

// ---------------- softmax over 4096, bf16 in -> bf16 probs (packed uint IO) ----------------
__global__ __launch_bounds__(256) void k_softmax(const u16* __restrict__ lg, u16* __restrict__ att){
  int row = blockIdx.x, t = threadIdx.x;
  const uint* p = (const uint*)(lg + (size_t)row*TOK);
  uint pv[8]; float v0[8], v1[8]; float mx = -1e30f;
  #pragma unroll
  for (int i = 0; i < 8; i++){
    pv[i] = p[t + i*256];
    v0[i] = bf2f((u16)(pv[i] & 0xFFFF));
    v1[i] = bf2f((u16)(pv[i] >> 16));
    mx = fmaxf(mx, fmaxf(v0[i], v1[i]));
  }
  int lane = t & 63, w = t >> 6;
  for (int o = 32; o; o >>= 1) mx = fmaxf(mx, __shfl_xor(mx, o, 64));
  __shared__ float sm[4]; __shared__ float ssum[4];
  if (lane == 0) sm[w] = mx;
  __syncthreads();
  mx = fmaxf(fmaxf(sm[0], sm[1]), fmaxf(sm[2], sm[3]));
  float s = 0.f;
  #pragma unroll
  for (int i = 0; i < 8; i++){
    v0[i] = expf(v0[i] - mx); v1[i] = expf(v1[i] - mx);
    s += v0[i] + v1[i];
  }
  s = wred_sum(s);
  if (lane == 0) ssum[w] = s;
  __syncthreads();
  s = ssum[0]+ssum[1]+ssum[2]+ssum[3];
  float inv = 1.f / s;
  uint* q = (uint*)(att + (size_t)row*TOK);
  #pragma unroll
  for (int i = 0; i < 8; i++){
    uint lo = f2bf(v0[i]*inv);
    uint hi = f2bf(v1[i]*inv);
    q[t + i*256] = lo | (hi << 16);
  }
}

// ---------------- final heads + Gram-Schmidt + assembly ----------------
__global__ __launch_bounds__(256) void k_final(
    const float* __restrict__ h4, const float* __restrict__ rot6d,
    const float* __restrict__ offW2, const float* __restrict__ offb2,
    const float* __restrict__ dW2, const float* __restrict__ db2,
    const float* __restrict__ sW2, const float* __restrict__ sb2,
    const float* __restrict__ K_cam, const float* __restrict__ useful,
    const float* __restrict__ maskf, const float* __restrict__ colf, const float* __restrict__ rowf,
    float* __restrict__ out)
{
  int bq = blockIdx.x, t = threadIdx.x, b = bq >> 4;
  float po0 = 0.f, po1 = 0.f, pd = 0.f, ps[11];
  #pragma unroll
  for (int j = 0; j < 11; j++) ps[j] = 0.f;
  const float* hrow = h4 + (size_t)bq*2048;
  for (int i = t; i < DD; i += 256){
    float ho = hrow[i];
    float hd = hrow[512 + i];
    float hs = hrow[1024 + i];
    po0 += ho*offW2[i*2]; po1 += ho*offW2[i*2+1];
    pd += hd*dW2[i];
    #pragma unroll
    for (int j = 0; j < 11; j++) ps[j] += hs*sW2[i*11+j];
  }
  __shared__ float sred[4][14];
  __shared__ float sout[14];
  int wv = t >> 6, ln = t & 63;
  float vals[14];
  vals[0] = po0; vals[1] = po1; vals[2] = pd;
  #pragma unroll
  for (int j = 0; j < 11; j++) vals[3+j] = ps[j];
  #pragma unroll
  for (int kk = 0; kk < 14; kk++){
    float r = wred_sum(vals[kk]);
    if (ln == 0) sred[wv][kk] = r;
  }
  __syncthreads();
  if (t < 14) sout[t] = sred[0][t]+sred[1][t]+sred[2][t]+sred[3][t];
  __syncthreads();
  float m = maskf[bq];
  if (t == 0){
    float off0 = sout[0] + offb2[0], off1 = sout[1] + offb2[1];
    float draw = sout[2] + db2[0];
    float l0 = (colf[bq] + 0.5f + off0) * 14.0f;
    float l1 = (rowf[bq] + 0.5f + off1) * 14.0f;
    float fx = K_cam[b*9+0], cx = K_cam[b*9+2], fy = K_cam[b*9+4], cy = K_cam[b*9+5];
    float dist = fx / fmaxf(expf(draw), 1e-5f);
    float tx = (l0 - cx) / fx * dist, ty = (l1 - cy) / fy * dist;
    float* o = out + (size_t)bq*OUTW;
    o[0] = l0*m; o[1] = l1*m; o[2] = off0*m; o[3] = off1*m; o[4] = dist*m;
    o[5] = tx*m; o[6] = ty*m; o[7] = dist*m;
    #pragma unroll
    for (int j = 0; j < 11; j++){ float sp = sout[3+j] + sb2[j]; o[8+j] = m / (1.f + expf(-sp)); }
  }
  if (t < NJ){
    const float* rp = rot6d + (size_t)bq*NROT + t*6;
    float a0 = rp[0], b0 = rp[1], a1 = rp[2], b1 = rp[3], a2 = rp[4], b2 = rp[5];
    float n0 = sqrtf(a0*a0 + a1*a1 + a2*a2);
    float i0 = 1.f / (n0 + 1e-8f);
    float u00 = a0*i0, u01 = a1*i0, u02 = a2*i0;
    float dt = b0*u00 + b1*u01 + b2*u02;
    float v0 = b0 - dt*u00, v1 = b1 - dt*u01, v2 = b2 - dt*u02;
    float n1 = sqrtf(v0*v0 + v1*v1 + v2*v2);
    float i1 = 1.f / (n1 + 1e-8f);
    float u10 = v0*i1, u11 = v1*i1, u12 = v2*i1;
    float u20 = u01*u12 - u02*u11;
    float u21 = u02*u10 - u00*u12;
    float u22 = u00*u11 - u01*u10;
    float um = useful[t], om = 1.f - um;
    float R00 = um*u00 + om, R01 = um*u10,      R02 = um*u20;
    float R10 = um*u01,      R11 = um*u11 + om, R12 = um*u21;
    float R20 = um*u02,      R21 = um*u12,      R22 = um*u22 + om;
    float* o = out + (size_t)bq*OUTW + 19 + t*9;
    o[0] = R00*m; o[1] = R01*m; o[2] = R02*m;
    o[3] = R10*m; o[4] = R11*m; o[5] = R12*m;
    o[6] = R20*m; o[7] = R21*m; o[8] = R22*m;
  }
}

extern "C" void kernel_launch(void* const* d_in, const int* in_sizes, int n_in,
                              void* d_out, int out_size, void* d_ws, size_t ws_size,
                              hipStream_t stream)
{
  const float* feat   = (const float*)d_in[0];
  const float* scores = (const float*)d_in[1];
  const float* K_cam  = (const float*)d_in[2];
  const float* pos_emb= (const float*)d_in[3];
  const float* Wtok   = (const float*)d_in[4];
  const float* btok   = (const float*)d_in[5];
  const float* Wq     = (const float*)d_in[6];
  const float* Wk     = (const float*)d_in[7];
  const float* Wv     = (const float*)d_in[8];
  const float* Wo     = (const float*)d_in[9];
  const float* g1     = (const float*)d_in[10];
  const float* b1n    = (const float*)d_in[11];
  const float* W1     = (const float*)d_in[12];
  const float* bf1    = (const float*)d_in[13];
  const float* W2     = (const float*)d_in[14];
  const float* bf2    = (const float*)d_in[15];
  const float* g2     = (const float*)d_in[16];
  const float* b2n    = (const float*)d_in[17];
  const float* offW1  = (const float*)d_in[18];
  const float* offb1  = (const float*)d_in[19];
  const float* offW2  = (const float*)d_in[20];
  const float* offb2  = (const float*)d_in[21];
  const float* dW1    = (const float*)d_in[22];
  const float* db1    = (const float*)d_in[23];
  const float* dW2    = (const float*)d_in[24];
  const float* db2    = (const float*)d_in[25];
  const float* sW1    = (const float*)d_in[26];
  const float* sb1    = (const float*)d_in[27];
  const float* sW2    = (const float*)d_in[28];
  const float* sb2    = (const float*)d_in[29];
  const float* pW1    = (const float*)d_in[30];
  const float* pb1    = (const float*)d_in[31];
  const float* pW2    = (const float*)d_in[32];
  const float* pb2    = (const float*)d_in[33];
  const float* ibp    = (const float*)d_in[34];
  const float* useful = (const float*)d_in[35];
  float* out = (float*)d_out;

  char* wsp = (char*)d_ws;
  size_t off = 0;
  auto alloc = [&](size_t bytes)->char*{
    char* p = wsp + off;
    off += (bytes + 255) & ~((size_t)255);
    return p;
  };
  int*   t_idx  = (int*)  alloc(BKQ*4);
  float* t_mask = (float*)alloc(BKQ*4);
  float* t_col  = (float*)alloc(BKQ*4);
  float* t_row  = (float*)alloc(BKQ*4);
  u16*   feat_bf= (u16*)  alloc((size_t)BB*TOK*CE*2);
  u16*   wtokT  = (u16*)  alloc((size_t)DD*CE*2);
  u16*   ctx_bf = (u16*)  alloc((size_t)BB*TOK*DD*2);
  u16*   ctxT_bf= (u16*)  alloc((size_t)BB*TOK*DD*2);
  u16*   ATb    = (u16*)  alloc((size_t)8192*DD*2);
  u16*   WVOb   = (u16*)  alloc((size_t)DD*8192*2);
  u16*   w1T    = (u16*)  alloc((size_t)LL*DD*MM*2);
  u16*   w2T    = (u16*)  alloc((size_t)LL*MM*DD*2);
  u16*   headsT = (u16*)  alloc((size_t)4*DD*DD*2);
  u16*   pw2T   = (u16*)  alloc((size_t)1024*DD*2);
  float* x      = (float*)alloc((size_t)BKQ*DD*4);
  u16*   x_bf   = (u16*)  alloc((size_t)BKQ*DD*2);
  u16*   z_bf   = (u16*)  alloc((size_t)BKQ*HH*DD*2);
  u16*   logits = (u16*)  alloc((size_t)BB*QH*TOK*2);
  u16*   att_bf = (u16*)  alloc((size_t)BB*QH*TOK*2);
  float* parts  = (float*)alloc((size_t)BB*8*QH*DD*4);
  u16*   c_flat = (u16*)  alloc((size_t)BKQ*8192*2);
  u16*   mid_bf = (u16*)  alloc((size_t)BKQ*MM*2);
  float* h4     = (float*)alloc((size_t)BKQ*2048*4);
  u16*   hp_bf  = (u16*)  alloc((size_t)BKQ*DD*2);
  float* hb4    = (float*)alloc(2048*4);
  float* cvec2  = (float*)alloc(1024*4);
  float* rot6d  = (float*)alloc((size_t)BKQ*NROT*4);
  if (off > ws_size) return;

  // job table for unified weight transposer
  PJobs J;
  int ntl = 0, nj = 0;
  auto addjob = [&](const float* s, u16* d, int R, int C){
    J.s[nj] = s; J.d[nj] = d; J.R[nj] = R; J.C[nj] = C; J.t0[nj] = ntl;
    ntl += ((R+31)/32) * ((C+31)/32);
    nj++;
  };
  addjob(Wtok, wtokT, CE, DD);
  for (int l = 0; l < LL; l++) addjob(W1 + (size_t)l*DD*MM, w1T + (size_t)l*MM*DD, DD, MM);
  for (int l = 0; l < LL; l++) addjob(W2 + (size_t)l*MM*DD, w2T + (size_t)l*DD*MM, MM, DD);
  addjob(offW1, headsT,            DD, DD);
  addjob(dW1,   headsT + DD*DD,    DD, DD);
  addjob(sW1,   headsT + 2*DD*DD,  DD, DD);
  addjob(pW1,   headsT + 3*DD*DD,  DD, DD);
  addjob(pW2,   pw2T, DD, NROT);
  J.t0[nj] = ntl; J.njobs = nj; J.ntiles = ntl;

  k_nms_topk<<<BB, 256, 0, stream>>>(scores, t_idx, t_mask, t_col, t_row);
  k_cvt_bf16<<<3072, 256, 0, stream>>>(feat, feat_bf, BB*TOK*CE/4);
  k_prepw<<<2048, 256, 0, stream>>>(J);
  k_gemm_emb<<<dim3(DD/128, (BB*TOK)/128, 1), 256, 0, stream>>>(feat_bf, wtokT, ctx_bf, btok, pos_emb);
  k_transp_b<<<dim3(DD/32, TOK/32, BB), 256, 0, stream>>>(ctx_bf, ctxT_bf, TOK, DD);
  k_misc<<<193, 256, 0, stream>>>(feat, Wtok, btok, pos_emb, t_idx, x, pW1, pb1, ibp, hb4,
                                  offb1, db1, sb1, pb2, cvec2);

  for (int l = 0; l < LL; l++){
    // AT = scale * Wq·Wk^T (per-head), then z = LN1(x) @ AT^T  (z layout [b][q*16+h][dout])
    k_wqk<<<1024, 256, 0, stream>>>(Wq + (size_t)l*DD*DD, Wk + (size_t)l*DD*DD, ATb);
    k_mf64<0,0,0,1,0,0,1><<<dim3(128,1), 256, 0, stream>>>(
        nullptr, x, g1 + l*DD, b1n + l*DD, ATb, nullptr,
        nullptr, z_bf, nullptr, 8192, DD, DD, DD, 1.f);
    // logits[b] = Z_b (256x512) @ ctx_b^T -> bf16
    k_gemm_bt64<1><<<dim3(TOK/64, 2, BB), 256, 0, stream>>>(
        z_bf, ctx_bf, nullptr, logits,
        DD, DD, DD, TOK, (long)QH*DD, (long)TOK*DD, (long)QH*TOK, 1);
    k_softmax<<<BB*QH, 256, 0, stream>>>(logits, att_bf);
    // parts[b*8+ks] = att_b @ ctxT_b^T over K-slice ks
    k_gemm_bt64<0><<<dim3(DD/64, 2, BB*8), 256, 0, stream>>>(
        att_bf, ctxT_bf, parts, nullptr,
        TOK/8, TOK, TOK, DD, (long)QH*TOK, (long)DD*TOK, (long)QH*DD, 8);
    // WVO = Wv·Wo (per-head), c_flat = sum_ks parts (bf16, [bq][h*512+Dc])
    k_wvo<<<1024, 256, 0, stream>>>(Wv + (size_t)l*DD*DD, Wo + (size_t)l*DD*DD, WVOb);
    k_red8<<<512, 256, 0, stream>>>(parts, c_flat);
    // x += c_flat @ WVO^T   (K=8192, ksplit=16, atomic)
    k_mf64<0,1,0,0,0,0,0><<<dim3(8,16), 256, 0, stream>>>(
        c_flat, nullptr, nullptr, nullptr, WVOb, nullptr,
        x, nullptr, nullptr, DD, 8192, 512, DD, 1.f);
    // mid = gelu(LN2(x) @ W1 + bf1)  -> bf16
    k_mf64<2,0,1,1,0,0,0><<<dim3(MM/64,1), 256, 0, stream>>>(
        nullptr, x, g2 + l*DD, b2n + l*DD, w1T + (size_t)l*DD*MM, bf1 + l*MM,
        nullptr, mid_bf, nullptr, MM, DD, DD, MM, 1.f);
    // x += mid @ W2 + bf2  (ksplit=8, atomic)
    k_mf64<0,1,0,0,0,0,0><<<dim3(8,8), 256, 0, stream>>>(
        mid_bf, nullptr, nullptr, nullptr, w2T + (size_t)l*MM*DD, bf2 + l*DD,
        x, nullptr, nullptr, DD, MM, MM/8, DD, 1.f);
  }

  // heads: h4 = relu(x @ [offW1|dW1|sW1|pW1] + hb4), with bf16 copy of the pose slice
  k_cvt_bf16<<<32, 256, 0, stream>>>(x, x_bf, BKQ*DD/4);
  k_mf64<1,0,0,0,0,1,0><<<dim3(32,1), 256, 0, stream>>>(
      x_bf, nullptr, nullptr, nullptr, headsT, hb4,
      h4, nullptr, hp_bf, 2048, DD, DD, 2048, 1.f);
  // rot6d = h_p @ pW2 + (pb2 + ibp)
  k_mf64<0,0,0,0,1,0,0><<<dim3(16,1), 256, 0, stream>>>(
      hp_bf, nullptr, nullptr, nullptr, pw2T, cvec2,
      rot6d, nullptr, nullptr, NROT, DD, DD, NROT, 1.f);
  k_final<<<BKQ, 256, 0, stream>>>(h4, rot6d, offW2, offb2, dW2, db2, sW2, sb2,
                                   K_cam, useful, t_mask, t_col, t_row, out);
}

// Round 9
// 911.395 us; speedup vs baseline: 4.7378x; 1.0584x over previous
//
#include <hip/hip_runtime.h>

typedef unsigned int uint;
typedef unsigned short u16;

#define BB 4
#define CE 384
#define DD 512
#define LL 8
#define HH 16
#define MM 2048
#define NJ 163
#define TOK 4096
#define BKQ 64
#define QH 256
#define OUTW 1486
#define NROT 978
#define QKSCALE 0.17677669529663687f

typedef __attribute__((ext_vector_type(8))) short short8;
typedef __attribute__((ext_vector_type(4))) float float4v;

static __device__ __forceinline__ u16 f2bf(float f){
  union { float f; uint u; } c; c.f = f;
  uint u = c.u;
  return (u16)((u + 0x7FFFu + ((u >> 16) & 1u)) >> 16);
}
static __device__ __forceinline__ float bf2f(u16 u){
  union { uint u; float f; } c; c.u = ((uint)u) << 16;
  return c.f;
}
static __device__ __forceinline__ float wred_sum(float v){
  for (int o = 32; o; o >>= 1) v += __shfl_xor(v, o, 64);
  return v;
}
static __device__ __forceinline__ void gl16(const void* g, void* l){
  __builtin_amdgcn_global_load_lds((const __attribute__((address_space(1))) void*)g,
                                   (__attribute__((address_space(3))) void*)l, 16, 0, 0);
}

// ---------------- NMS + top-k (register scan, exact fp32, stable ties) ----------------
__global__ __launch_bounds__(256) void k_nms_topk(const float* __restrict__ scores,
    int* __restrict__ oidx, float* __restrict__ omask, float* __restrict__ ocol, float* __restrict__ orow)
{
  int b = blockIdx.x, t = threadIdx.x;
  __shared__ float sraw[4096];
  __shared__ float sv[4]; __shared__ int si[4]; __shared__ int swin;
  const float* sp = scores + (size_t)b * 4096;
  for (int i = t; i < 4096; i += 256) sraw[i] = sp[i];
  __syncthreads();
  float v[16];
  #pragma unroll
  for (int j = 0; j < 16; j++){
    int i = t + j*256;
    int r = i >> 6, c = i & 63;
    float mx = -1e30f;
    for (int dr = -1; dr <= 1; dr++){
      int rr = r + dr; if (rr < 0 || rr > 63) continue;
      for (int dc = -1; dc <= 1; dc++){
        int cc = c + dc; if (cc < 0 || cc > 63) continue;
        mx = fmaxf(mx, sraw[rr*64+cc]);
      }
    }
    float s = sraw[i];
    v[j] = (s == mx) ? s : 0.0f;
  }
  int lane = t & 63, wv = t >> 6;
  for (int iter = 0; iter < 16; iter++){
    float best = -1e30f; int bi_ = 1 << 30;
    #pragma unroll
    for (int j = 0; j < 16; j++){
      if (v[j] > best){ best = v[j]; bi_ = t + j*256; }
    }
    #pragma unroll
    for (int o = 32; o; o >>= 1){
      float ov = __shfl_xor(best, o, 64);
      int oi = __shfl_xor(bi_, o, 64);
      if (ov > best || (ov == best && oi < bi_)){ best = ov; bi_ = oi; }
    }
    if (lane == 0){ sv[wv] = best; si[wv] = bi_; }
    __syncthreads();
    if (t == 0){
      float bb = sv[0]; int ii = si[0];
      for (int k = 1; k < 4; k++){
        if (sv[k] > bb || (sv[k] == bb && si[k] < ii)){ bb = sv[k]; ii = si[k]; }
      }
      oidx[b*16+iter] = ii;
      omask[b*16+iter] = (bb >= 0.3f) ? 1.f : 0.f;
      ocol[b*16+iter] = (float)(ii & 63);
      orow[b*16+iter] = (float)(ii >> 6);
      swin = ii;
    }
    __syncthreads();
    int wi = swin;
    if ((wi & 255) == t) v[wi >> 8] = -1e30f;
    __syncthreads();
  }
}

// ---------------- fp32 -> bf16 convert (used for x -> x_bf tail only) ----------------
__global__ __launch_bounds__(256) void k_cvt_bf16(const float* __restrict__ in, u16* __restrict__ out, int n4){
  int i = blockIdx.x*256 + threadIdx.x;
  int stride = gridDim.x*256;
  for (int j = i; j < n4; j += stride){
    float4 v = ((const float4*)in)[j];
    ushort4 o;
    o.x = f2bf(v.x); o.y = f2bf(v.y); o.z = f2bf(v.z); o.w = f2bf(v.w);
    ((ushort4*)out)[j] = o;
  }
}

// ---------------- unified prep: transpose jobs + pose-const + bias packing ----------------
struct PJobs {
  const float* s[24]; u16* d[24];
  int R[24], C[24], t0[25];
  int njobs, ntiles;
};
__global__ __launch_bounds__(256) void k_prep_all(PJobs J,
    const float* __restrict__ pW1, const float* __restrict__ pb1,
    const float* __restrict__ ibp, float* __restrict__ hb4,
    const float* __restrict__ offb1, const float* __restrict__ db1, const float* __restrict__ sb1,
    const float* __restrict__ pb2, float* __restrict__ cvec2)
{
  int bid = blockIdx.x, t = threadIdx.x;
  if (bid < 128){
    int d = bid*4 + (t >> 6);
    int ln = t & 63;
    float acc = 0.f;
    for (int i = ln; i < NJ*6; i += 64) acc += ibp[i] * pW1[(size_t)(DD+i)*DD + d];
    acc = wred_sum(acc);
    if (ln == 0) hb4[1536 + d] = acc + pb1[d];
  } else if (bid == 128){
    for (int i = t; i < 1536; i += 256)
      hb4[i] = (i < 512) ? offb1[i] : (i < 1024 ? db1[i-512] : sb1[i-1024]);
    for (int i = t; i < 1024; i += 256)
      cvec2[i] = (i < NJ*6) ? (pb2[i] + ibp[i]) : 0.f;
  }
  __shared__ float tile[32][33];
  for (int g = bid; g < J.ntiles; g += gridDim.x){
    int j = 0;
    while (g >= J.t0[j+1]) j++;
    int ti = g - J.t0[j];
    int C_ = J.C[j], R_ = J.R[j];
    int tC = (C_ + 31) >> 5;
    int ry = ti / tC, cx = ti - ry*tC;
    int c0 = cx*32, r0 = ry*32;
    int tx = t & 31, ty = t >> 5;
    const float* src = J.s[j]; u16* dst = J.d[j];
    for (int i = 0; i < 32; i += 8){
      float v = 0.f;
      if (c0+tx < C_) v = src[(size_t)(r0+ty+i)*C_ + c0+tx];
      tile[ty+i][tx] = v;
    }
    __syncthreads();
    for (int i = 0; i < 32; i += 8){
      if (c0+ty+i < C_) dst[(size_t)(c0+ty+i)*R_ + r0+tx] = f2bf(tile[tx][ty+i]);
    }
    __syncthreads();
  }
}

// ---------------- AT/WVO prep merged (2048 blocks) ----------------
__global__ __launch_bounds__(256) void k_wqkvo(const float* __restrict__ wq, const float* __restrict__ wk,
    const float* __restrict__ wv, const float* __restrict__ wo,
    u16* __restrict__ AT, u16* __restrict__ WVOT)
{
  __shared__ __align__(16) u16 As[2560];
  __shared__ __align__(16) u16 Bs[2560];
  int t = threadIdx.x;
  int lane = t & 63, w = t >> 6, lr = lane & 15, lk = lane >> 4;
  float4v acc[4];
  float4v z4 = {0.f,0.f,0.f,0.f};
  acc[0]=z4; acc[1]=z4; acc[2]=z4; acc[3]=z4;
  if (blockIdx.x < 1024){
    int id = blockIdx.x;
    int rt = id & 127, dt = id >> 7;
    int h = rt >> 3, dout0 = (rt & 7)*64, din0 = dt*64;
    int r = t >> 2, c0 = (t & 3)*8;
    {
      float4 u0 = *(const float4*)(wk + (size_t)(dout0+r)*DD + h*32 + c0);
      float4 u1 = *(const float4*)(wk + (size_t)(dout0+r)*DD + h*32 + c0 + 4);
      u16* d = As + r*40 + c0;
      d[0]=f2bf(u0.x); d[1]=f2bf(u0.y); d[2]=f2bf(u0.z); d[3]=f2bf(u0.w);
      d[4]=f2bf(u1.x); d[5]=f2bf(u1.y); d[6]=f2bf(u1.z); d[7]=f2bf(u1.w);
      float4 v0 = *(const float4*)(wq + (size_t)(din0+r)*DD + h*32 + c0);
      float4 v1 = *(const float4*)(wq + (size_t)(din0+r)*DD + h*32 + c0 + 4);
      u16* e = Bs + r*40 + c0;
      e[0]=f2bf(v0.x); e[1]=f2bf(v0.y); e[2]=f2bf(v0.z); e[3]=f2bf(v0.w);
      e[4]=f2bf(v1.x); e[5]=f2bf(v1.y); e[6]=f2bf(v1.z); e[7]=f2bf(v1.w);
    }
    __syncthreads();
    short8 af = *(const short8*)&As[(w*16+lr)*40 + lk*8];
    #pragma unroll
    for (int nf = 0; nf < 4; nf++){
      short8 bf8 = *(const short8*)&Bs[(nf*16+lr)*40 + lk*8];
      acc[nf] = __builtin_amdgcn_mfma_f32_16x16x32_bf16(af, bf8, acc[nf], 0, 0, 0);
    }
    #pragma unroll
    for (int nf = 0; nf < 4; nf++){
      #pragma unroll
      for (int jj = 0; jj < 4; jj++){
        int row = w*16 + lk*4 + jj;
        AT[(size_t)(h*512 + dout0 + row)*DD + din0 + nf*16 + lr] = f2bf(acc[nf][jj]*QKSCALE);
      }
    }
  } else {
    int id = blockIdx.x - 1024;
    int ct = id & 127, dt = id >> 7;
    int h = ct >> 3, Dc0 = (ct & 7)*64, dout0 = dt*64;
    {
      int c = t >> 3, d8 = (t & 7)*8;
      float4 a0 = *(const float4*)(wo + (size_t)(h*32+c)*DD + dout0 + d8);
      float4 a1 = *(const float4*)(wo + (size_t)(h*32+c)*DD + dout0 + d8 + 4);
      As[(d8+0)*40 + c] = f2bf(a0.x);
      As[(d8+1)*40 + c] = f2bf(a0.y);
      As[(d8+2)*40 + c] = f2bf(a0.z);
      As[(d8+3)*40 + c] = f2bf(a0.w);
      As[(d8+4)*40 + c] = f2bf(a1.x);
      As[(d8+5)*40 + c] = f2bf(a1.y);
      As[(d8+6)*40 + c] = f2bf(a1.z);
      As[(d8+7)*40 + c] = f2bf(a1.w);
      int r = t >> 2, c0 = (t & 3)*8;
      float4 v0 = *(const float4*)(wv + (size_t)(Dc0+r)*DD + h*32 + c0);
      float4 v1 = *(const float4*)(wv + (size_t)(Dc0+r)*DD + h*32 + c0 + 4);
      u16* e = Bs + r*40 + c0;
      e[0]=f2bf(v0.x); e[1]=f2bf(v0.y); e[2]=f2bf(v0.z); e[3]=f2bf(v0.w);
      e[4]=f2bf(v1.x); e[5]=f2bf(v1.y); e[6]=f2bf(v1.z); e[7]=f2bf(v1.w);
    }
    __syncthreads();
    short8 af = *(const short8*)&As[(w*16+lr)*40 + lk*8];
    #pragma unroll
    for (int nf = 0; nf < 4; nf++){
      short8 bf8 = *(const short8*)&Bs[(nf*16+lr)*40 + lk*8];
      acc[nf] = __builtin_amdgcn_mfma_f32_16x16x32_bf16(af, bf8, acc[nf], 0, 0, 0);
    }
    #pragma unroll
    for (int nf = 0; nf < 4; nf++){
      #pragma unroll
      for (int jj = 0; jj < 4; jj++){
        int row = w*16 + lk*4 + jj;
        WVOT[(size_t)(dout0 + row)*8192 + h*512 + Dc0 + nf*16 + lr] = f2bf(acc[nf][jj]);
      }
    }
  }
}

// ---------------- reduce 8 PV split-K bf16 partials -> c_flat bf16 [bq][h*512+Dc] ----------------
__global__ __launch_bounds__(256) void k_red8(const u16* __restrict__ parts, u16* __restrict__ cf){
  int i4 = blockIdx.x*256 + threadIdx.x;   // 131072 groups of 4
  int elem = i4*4;
  int row = elem >> 13, col = elem & 8191;
  int b = row >> 4, q = row & 15, h = col >> 9, Dc = col & 511;
  const u16* src = parts + ((size_t)b*8)*131072 + (size_t)(q*16+h)*512 + Dc;
  float s0 = 0.f, s1 = 0.f, s2 = 0.f, s3 = 0.f;
  #pragma unroll
  for (int ks = 0; ks < 8; ks++){
    ushort4 g = *(const ushort4*)(src + (size_t)ks*131072);
    s0 += bf2f(g.x); s1 += bf2f(g.y); s2 += bf2f(g.z); s3 += bf2f(g.w);
  }
  ushort4 o;
  o.x = f2bf(s0); o.y = f2bf(s1); o.z = f2bf(s2); o.w = f2bf(s3);
  *(ushort4*)&cf[(size_t)row*8192 + col] = o;
}

// ---------------- ctx embed GEMM: ctx = feat(fp32) @ wtokT^T + btok + pos_emb -> bf16 ctx + ctxT ----------------
__global__ __launch_bounds__(256) void k_gemm_emb(
    const float* __restrict__ feat, const u16* __restrict__ Bt,
    u16* __restrict__ ctx, u16* __restrict__ ctxT,
    const float* __restrict__ ep1, const float* __restrict__ ep2)
{
  __shared__ __align__(16) u16 SM[16640];   // As 128x64 | Bs 128x64 ; reused as 128x130 transpose tile
  u16* As = SM;
  u16* Bs = SM + 8192;
  int m0 = blockIdx.y*128, n0 = blockIdx.x*128;
  int t = threadIdx.x, lane = t & 63, wave = t >> 6;
  int wr = wave >> 1, wc = wave & 1;
  int lr = lane & 15, lk = lane >> 4;
  int sr8 = t >> 3, sl = t & 7;
  int sw = ((sl ^ (sr8 & 7)) * 8);
  float4v acc[4][4];
  float4v z4 = {0.f, 0.f, 0.f, 0.f};
  #pragma unroll
  for (int i = 0; i < 4; i++)
    #pragma unroll
    for (int j = 0; j < 4; j++) acc[i][j] = z4;
  for (int kt = 0; kt < CE; kt += 64){
    __syncthreads();
    // A: fp32 reg-stage + convert (swizzled to match read slots)
    #pragma unroll
    for (int p = 0; p < 8; p++){
      int r = (t >> 4) + p*16, f4 = t & 15;
      float4 v = *(const float4*)&feat[(size_t)(m0+r)*CE + kt + f4*4];
      int dc = ((f4 >> 1) ^ (r & 7))*8 + (f4 & 1)*4;
      ushort4 o; o.x = f2bf(v.x); o.y = f2bf(v.y); o.z = f2bf(v.z); o.w = f2bf(v.w);
      *(ushort4*)&As[r*64 + dc] = o;
    }
    #pragma unroll
    for (int rg = 0; rg < 4; rg++)
      gl16(Bt + (size_t)(n0 + rg*32 + sr8)*CE + kt + sw, Bs + rg*2048 + 8*t);
    __syncthreads();
    #pragma unroll
    for (int s = 0; s < 2; s++){
      int slot = ((s*4 + lk) ^ (lr & 7)) * 8;
      short8 af[4], bfr[4];
      #pragma unroll
      for (int i = 0; i < 4; i++) af[i] = *(const short8*)&As[(wr*64 + i*16 + lr)*64 + slot];
      #pragma unroll
      for (int j = 0; j < 4; j++) bfr[j] = *(const short8*)&Bs[(wc*64 + j*16 + lr)*64 + slot];
      #pragma unroll
      for (int i = 0; i < 4; i++)
        #pragma unroll
        for (int j = 0; j < 4; j++)
          acc[i][j] = __builtin_amdgcn_mfma_f32_16x16x32_bf16(af[i], bfr[j], acc[i][j], 0, 0, 0);
    }
  }
  __syncthreads();
  #pragma unroll
  for (int i = 0; i < 4; i++){
    int rbase = m0 + wr*64 + i*16 + lk*4;
    #pragma unroll
    for (int j = 0; j < 4; j++){
      int cc = n0 + wc*64 + j*16 + lr;
      #pragma unroll
      for (int jj = 0; jj < 4; jj++){
        int rr = rbase + jj;
        float vv = acc[i][j][jj] + ep1[cc] + ep2[(size_t)(rr & 4095)*DD + cc];
        u16 bv = f2bf(vv);
        ctx[(size_t)rr*DD + cc] = bv;
        SM[(cc - n0)*130 + (rr - m0)] = bv;
      }
    }
  }
  __syncthreads();
  int b = m0 >> 12, tok0 = m0 & 4095;
  int tx = t & 63, ty = t >> 6;
  #pragma unroll 4
  for (int it = 0; it < 32; it++){
    int c = ty*32 + it;
    uint vv = *(const uint*)&SM[c*130 + tx*2];
    *(uint*)&ctxT[((size_t)b*DD + n0 + c)*TOK + tok0 + tx*2] = vv;
  }
}

// ---------------- gather x0 from ctx rows (bf16 -> fp32) ----------------
__global__ __launch_bounds__(256) void k_gather2(const u16* __restrict__ ctx, const int* __restrict__ oidx,
    float* __restrict__ x)
{
  int bq = blockIdx.x, t = threadIdx.x;
  int b = bq >> 4, tok = oidx[bq];
  uint v = ((const uint*)(ctx + ((size_t)b*TOK + tok)*DD))[t];
  float2 o; o.x = bf2f((u16)(v & 0xFFFF)); o.y = bf2f((u16)(v >> 16));
  *(float2*)&x[(size_t)bq*DD + t*2] = o;
}

// ---------------- MFMA GEMM, 128(M) x 64(N) tiles: C = A(MxK) @ Bt(NxK)^T ----------------
// EPI 0: fp32 store slice bz.  EPI 1: bf16 store batch slice.  EPI 2: bf16 store slice bz.
template<int EPI>
__global__ __launch_bounds__(256) void k_gemm_bt64(
    const u16* __restrict__ A, const u16* __restrict__ Bt,
    float* __restrict__ C, u16* __restrict__ Cb,
    int Kslice, int lda, int ldb, int ldc,
    long sA, long sB, long sC, int ksplit)
{
  int bz = blockIdx.z;
  int batch = bz / ksplit, ks = bz - batch*ksplit;
  const u16* Ab = A + (size_t)batch*sA + (size_t)ks*Kslice;
  const u16* Bb = Bt + (size_t)batch*sB + (size_t)ks*Kslice;
  int m0 = blockIdx.y*128, n0 = blockIdx.x*64;
  __shared__ __align__(16) u16 As[128*64];
  __shared__ __align__(16) u16 Bs[64*64];
  int t = threadIdx.x, lane = t & 63, w = t >> 6;
  int lr = lane & 15, lk = lane >> 4;
  int sr8 = t >> 3, sl = t & 7;
  int sw = ((sl ^ (sr8 & 7)) * 8);
  float4v acc[2][4];
  float4v z4 = {0.f,0.f,0.f,0.f};
  #pragma unroll
  for (int i = 0; i < 2; i++)
    #pragma unroll
    for (int j = 0; j < 4; j++) acc[i][j] = z4;

  for (int kt = 0; kt < Kslice; kt += 64){
    __syncthreads();
    #pragma unroll
    for (int rg = 0; rg < 4; rg++)
      gl16(Ab + (size_t)(m0 + rg*32 + sr8)*lda + kt + sw, As + rg*2048 + 8*t);
    #pragma unroll
    for (int rg = 0; rg < 2; rg++)
      gl16(Bb + (size_t)(n0 + rg*32 + sr8)*ldb + kt + sw, Bs + rg*2048 + 8*t);
    __syncthreads();
    #pragma unroll
    for (int s = 0; s < 2; s++){
      int slot = ((s*4 + lk) ^ (lr & 7)) * 8;
      short8 af[2], bfr[4];
      #pragma unroll
      for (int i = 0; i < 2; i++) af[i] = *(const short8*)&As[(w*32 + i*16 + lr)*64 + slot];
      #pragma unroll
      for (int j = 0; j < 4; j++) bfr[j] = *(const short8*)&Bs[(j*16 + lr)*64 + slot];
      #pragma unroll
      for (int i = 0; i < 2; i++)
        #pragma unroll
        for (int j = 0; j < 4; j++)
          acc[i][j] = __builtin_amdgcn_mfma_f32_16x16x32_bf16(af[i], bfr[j], acc[i][j], 0, 0, 0);
    }
  }
  #pragma unroll
  for (int i = 0; i < 2; i++){
    int rbase = m0 + w*32 + i*16 + lk*4;
    #pragma unroll
    for (int j = 0; j < 4; j++){
      int cc = n0 + j*16 + lr;
      #pragma unroll
      for (int jj = 0; jj < 4; jj++){
        int rr = rbase + jj;
        if (EPI == 0) C[(size_t)bz*sC + (size_t)rr*ldc + cc] = acc[i][j][jj];
        else if (EPI == 1) Cb[(size_t)batch*sC + (size_t)rr*ldc + cc] = f2bf(acc[i][j][jj]);
        else Cb[(size_t)bz*sC + (size_t)rr*ldc + cc] = f2bf(acc[i][j][jj]);
      }
    }
  }
}

// ---------------- skinny MFMA GEMM: C(64 x N) = A(64 x K) @ Bt(N x K)^T ----------------
// ACT: 0 none, 1 relu, 2 gelu.  RES: 0 store, 1 atomicAdd.  OUTB: bf16 out.
// DOLN: A = LN(xf)*g+b in-block.  NG: guard col<N.  HPB: bf16 copy of cols>=1536.
// ZMAP: store bf16 into z layout [b][q*16+h][dout] (col = h*512+dout).
template<int ACT, int RES, int OUTB, int DOLN, int NG, int HPB, int ZMAP = 0>
__global__ __launch_bounds__(256) void k_mf64(
    const u16* __restrict__ A, const float* __restrict__ xf,
    const float* __restrict__ g, const float* __restrict__ bb,
    const u16* __restrict__ Bt, const float* __restrict__ bias,
    float* __restrict__ C, u16* __restrict__ Cb, u16* __restrict__ Cb2,
    int N, int K, int kper, int ldc, float alpha)
{
  __shared__ __align__(16) u16 Asl[DOLN ? 64*520 : 64*64];
  __shared__ __align__(16) u16 Bs[64*64];
  int t = threadIdx.x, lane = t & 63, w = t >> 6;
  int lr = lane & 15, lk = lane >> 4;
  int n0 = blockIdx.x*64;
  int ks = blockIdx.y, kbeg = ks*kper;
  int sr8 = t >> 3, sl = t & 7;
  int sw = ((sl ^ (sr8 & 7)) * 8);

  if (DOLN){
    for (int rr = 0; rr < 16; rr++){
      int row = w*16 + rr;
      const float* xr = xf + (size_t)row*DD;
      float4 v0 = *(const float4*)(xr + lane*4);
      float4 v1 = *(const float4*)(xr + 256 + lane*4);
      float s = v0.x+v0.y+v0.z+v0.w + v1.x+v1.y+v1.z+v1.w;
      s = wred_sum(s);
      float mu = s * (1.f/DD);
      float d0=v0.x-mu, d1=v0.y-mu, d2=v0.z-mu, d3=v0.w-mu;
      float e0=v1.x-mu, e1=v1.y-mu, e2=v1.z-mu, e3=v1.w-mu;
      float q = d0*d0+d1*d1+d2*d2+d3*d3 + e0*e0+e1*e1+e2*e2+e3*e3;
      q = wred_sum(q);
      float inv = rsqrtf(q * (1.f/DD) + 1e-5f);
      float4 g0 = *(const float4*)(g + lane*4);
      float4 g1 = *(const float4*)(g + 256 + lane*4);
      float4 b0 = *(const float4*)(bb + lane*4);
      float4 b1 = *(const float4*)(bb + 256 + lane*4);
      u16* dst = &Asl[row*520];
      dst[lane*4+0] = f2bf(d0*inv*g0.x + b0.x);
      dst[lane*4+1] = f2bf(d1*inv*g0.y + b0.y);
      dst[lane*4+2] = f2bf(d2*inv*g0.z + b0.z);
      dst[lane*4+3] = f2bf(d3*inv*g0.w + b0.w);
      dst[256+lane*4+0] = f2bf(e0*inv*g1.x + b1.x);
      dst[256+lane*4+1] = f2bf(e1*inv*g1.y + b1.y);
      dst[256+lane*4+2] = f2bf(e2*inv*g1.z + b1.z);
      dst[256+lane*4+3] = f2bf(e3*inv*g1.w + b1.w);
    }
  }

  float4v acc[4];
  float4v z4 = {0.f,0.f,0.f,0.f};
  acc[0]=z4; acc[1]=z4; acc[2]=z4; acc[3]=z4;

  for (int kc = kbeg; kc < kbeg + kper; kc += 64){
    __syncthreads();
    if (!DOLN){
      gl16(A + (size_t)sr8*K + kc + sw,        (u16*)Asl + 8*t);
      gl16(A + (size_t)(32+sr8)*K + kc + sw,   (u16*)Asl + 2048 + 8*t);
    }
    gl16(Bt + (size_t)(n0+sr8)*K + kc + sw,      (u16*)Bs + 8*t);
    gl16(Bt + (size_t)(n0+32+sr8)*K + kc + sw,   (u16*)Bs + 2048 + 8*t);
    __syncthreads();
    #pragma unroll
    for (int s = 0; s < 2; s++){
      int slot = ((s*4 + lk) ^ (lr & 7)) * 8;
      short8 af;
      if (DOLN) af = *(const short8*)&Asl[(w*16+lr)*520 + kc + s*32 + lk*8];
      else      af = *(const short8*)&Asl[(w*16+lr)*64 + slot];
      #pragma unroll
      for (int nf = 0; nf < 4; nf++){
        short8 bf8 = *(const short8*)&Bs[(nf*16+lr)*64 + slot];
        acc[nf] = __builtin_amdgcn_mfma_f32_16x16x32_bf16(af, bf8, acc[nf], 0, 0, 0);
      }
    }
  }
  #pragma unroll
  for (int nf = 0; nf < 4; nf++){
    int col = n0 + nf*16 + lr;
    float bsv = (bias && ks == 0) ? bias[col] : 0.f;
    #pragma unroll
    for (int jj = 0; jj < 4; jj++){
      int row = w*16 + lk*4 + jj;
      float v = acc[nf][jj]*alpha + bsv;
      if (ACT == 1) v = fmaxf(v, 0.f);
      else if (ACT == 2) v = 0.5f*v*(1.f + tanhf(0.7978845608028654f*(v + 0.044715f*v*v*v)));
      if (NG && col >= N) continue;
      if (ZMAP){
        int b_ = row >> 4, q_ = row & 15, h_ = col >> 9, d_ = col & 511;
        Cb[((size_t)b_*QH + (q_ << 4) + h_)*DD + d_] = f2bf(v);
        continue;
      }
      size_t o = (size_t)row*ldc + col;
      if (OUTB == 1) Cb[o] = f2bf(v);
      else if (RES == 0) C[o] = v;
      else atomicAdd(&C[o], v);
      if (HPB && col >= 1536) Cb2[(size_t)row*DD + (col - 1536)] = f2bf(v);
    }
  }
}

// ---------------- softmax over 4096, bf16 in -> bf16 probs (packed uint IO) ----------------
__global__ __launch_bounds__(256) void k_softmax(const u16* __restrict__ lg, u16* __restrict__ att){
  int row = blockIdx.x, t = threadIdx.x;
  const uint* p = (const uint*)(lg + (size_t)row*TOK);
  uint pv[8]; float v0[8], v1[8]; float mx = -1e30f;
  #pragma unroll
  for (int i = 0; i < 8; i++){
    pv[i] = p[t + i*256];
    v0[i] = bf2f((u16)(pv[i] & 0xFFFF));
    v1[i] = bf2f((u16)(pv[i] >> 16));
    mx = fmaxf(mx, fmaxf(v0[i], v1[i]));
  }
  int lane = t & 63, w = t >> 6;
  for (int o = 32; o; o >>= 1) mx = fmaxf(mx, __shfl_xor(mx, o, 64));
  __shared__ float sm[4]; __shared__ float ssum[4];
  if (lane == 0) sm[w] = mx;
  __syncthreads();
  mx = fmaxf(fmaxf(sm[0], sm[1]), fmaxf(sm[2], sm[3]));
  float s = 0.f;
  #pragma unroll
  for (int i = 0; i < 8; i++){
    v0[i] = expf(v0[i] - mx); v1[i] = expf(v1[i] - mx);
    s += v0[i] + v1[i];
  }
  s = wred_sum(s);
  if (lane == 0) ssum[w] = s;
  __syncthreads();
  s = ssum[0]+ssum[1]+ssum[2]+ssum[3];
  float inv = 1.f / s;
  uint* q = (uint*)(att + (size_t)row*TOK);
  #pragma unroll
  for (int i = 0; i < 8; i++){
    uint lo = f2bf(v0[i]*inv);
    uint hi = f2bf(v1[i]*inv);
    q[t + i*256] = lo | (hi << 16);
  }
}

// ---------------- final heads + Gram-Schmidt + assembly ----------------
__global__ __launch_bounds__(256) void k_final(
    const float* __restrict__ h4, const float* __restrict__ rot6d,
    const float* __restrict__ offW2, const float* __restrict__ offb2,
    const float* __restrict__ dW2, const float* __restrict__ db2,
    const float* __restrict__ sW2, const float* __restrict__ sb2,
    const float* __restrict__ K_cam, const float* __restrict__ useful,
    const float* __restrict__ maskf, const float* __restrict__ colf, const float* __restrict__ rowf,
    float* __restrict__ out)
{
  int bq = blockIdx.x, t = threadIdx.x, b = bq >> 4;
  float po0 = 0.f, po1 = 0.f, pd = 0.f, ps[11];
  #pragma unroll
  for (int j = 0; j < 11; j++) ps[j] = 0.f;
  const float* hrow = h4 + (size_t)bq*2048;
  for (int i = t; i < DD; i += 256){
    float ho = hrow[i];
    float hd = hrow[512 + i];
    float hs = hrow[1024 + i];
    po0 += ho*offW2[i*2]; po1 += ho*offW2[i*2+1];
    pd += hd*dW2[i];
    #pragma unroll
    for (int j = 0; j < 11; j++) ps[j] += hs*sW2[i*11+j];
  }
  __shared__ float sred[4][14];
  __shared__ float sout[14];
  int wv = t >> 6, ln = t & 63;
  float vals[14];
  vals[0] = po0; vals[1] = po1; vals[2] = pd;
  #pragma unroll
  for (int j = 0; j < 11; j++) vals[3+j] = ps[j];
  #pragma unroll
  for (int kk = 0; kk < 14; kk++){
    float r = wred_sum(vals[kk]);
    if (ln == 0) sred[wv][kk] = r;
  }
  __syncthreads();
  if (t < 14) sout[t] = sred[0][t]+sred[1][t]+sred[2][t]+sred[3][t];
  __syncthreads();
  float m = maskf[bq];
  if (t == 0){
    float off0 = sout[0] + offb2[0], off1 = sout[1] + offb2[1];
    float draw = sout[2] + db2[0];
    float l0 = (colf[bq] + 0.5f + off0) * 14.0f;
    float l1 = (rowf[bq] + 0.5f + off1) * 14.0f;
    float fx = K_cam[b*9+0], cx = K_cam[b*9+2], fy = K_cam[b*9+4], cy = K_cam[b*9+5];
    float dist = fx / fmaxf(expf(draw), 1e-5f);
    float tx = (l0 - cx) / fx * dist, ty = (l1 - cy) / fy * dist;
    float* o = out + (size_t)bq*OUTW;
    o[0] = l0*m; o[1] = l1*m; o[2] = off0*m; o[3] = off1*m; o[4] = dist*m;
    o[5] = tx*m; o[6] = ty*m; o[7] = dist*m;
    #pragma unroll
    for (int j = 0; j < 11; j++){ float sp = sout[3+j] + sb2[j]; o[8+j] = m / (1.f + expf(-sp)); }
  }
  if (t < NJ){
    const float* rp = rot6d + (size_t)bq*NROT + t*6;
    float a0 = rp[0], b0 = rp[1], a1 = rp[2], b1 = rp[3], a2 = rp[4], b2 = rp[5];
    float n0 = sqrtf(a0*a0 + a1*a1 + a2*a2);
    float i0 = 1.f / (n0 + 1e-8f);
    float u00 = a0*i0, u01 = a1*i0, u02 = a2*i0;
    float dt = b0*u00 + b1*u01 + b2*u02;
    float v0 = b0 - dt*u00, v1 = b1 - dt*u01, v2 = b2 - dt*u02;
    float n1 = sqrtf(v0*v0 + v1*v1 + v2*v2);
    float i1 = 1.f / (n1 + 1e-8f);
    float u10 = v0*i1, u11 = v1*i1, u12 = v2*i1;
    float u20 = u01*u12 - u02*u11;
    float u21 = u02*u10 - u00*u12;
    float u22 = u00*u11 - u01*u10;
    float um = useful[t], om = 1.f - um;
    float R00 = um*u00 + om, R01 = um*u10,      R02 = um*u20;
    float R10 = um*u01,      R11 = um*u11 + om, R12 = um*u21;
    float R20 = um*u02,      R21 = um*u12,      R22 = um*u22 + om;
    float* o = out + (size_t)bq*OUTW + 19 + t*9;
    o[0] = R00*m; o[1] = R01*m; o[2] = R02*m;
    o[3] = R10*m; o[4] = R11*m; o[5] = R12*m;
    o[6] = R20*m; o[7] = R21*m; o[8] = R22*m;
  }
}

extern "C" void kernel_launch(void* const* d_in, const int* in_sizes, int n_in,
                              void* d_out, int out_size, void* d_ws, size_t ws_size,
                              hipStream_t stream)
{
  const float* feat   = (const float*)d_in[0];
  const float* scores = (const float*)d_in[1];
  const float* K_cam  = (const float*)d_in[2];
  const float* pos_emb= (const float*)d_in[3];
  const float* Wtok   = (const float*)d_in[4];
  const float* btok   = (const float*)d_in[5];
  const float* Wq     = (const float*)d_in[6];
  const float* Wk     = (const float*)d_in[7];
  const float* Wv     = (const float*)d_in[8];
  const float* Wo     = (const float*)d_in[9];
  const float* g1     = (const float*)d_in[10];
  const float* b1n    = (const float*)d_in[11];
  const float* W1     = (const float*)d_in[12];
  const float* bf1    = (const float*)d_in[13];
  const float* W2     = (const float*)d_in[14];
  const float* bf2    = (const float*)d_in[15];
  const float* g2     = (const float*)d_in[16];
  const float* b2n    = (const float*)d_in[17];
  const float* offW1  = (const float*)d_in[18];
  const float* offb1  = (const float*)d_in[19];
  const float* offW2  = (const float*)d_in[20];
  const float* offb2  = (const float*)d_in[21];
  const float* dW1    = (const float*)d_in[22];
  const float* db1    = (const float*)d_in[23];
  const float* dW2    = (const float*)d_in[24];
  const float* db2    = (const float*)d_in[25];
  const float* sW1    = (const float*)d_in[26];
  const float* sb1    = (const float*)d_in[27];
  const float* sW2    = (const float*)d_in[28];
  const float* sb2    = (const float*)d_in[29];
  const float* pW1    = (const float*)d_in[30];
  const float* pb1    = (const float*)d_in[31];
  const float* pW2    = (const float*)d_in[32];
  const float* pb2    = (const float*)d_in[33];
  const float* ibp    = (const float*)d_in[34];
  const float* useful = (const float*)d_in[35];
  float* out = (float*)d_out;

  char* wsp = (char*)d_ws;
  size_t off = 0;
  auto alloc = [&](size_t bytes)->char*{
    char* p = wsp + off;
    off += (bytes + 255) & ~((size_t)255);
    return p;
  };
  int*   t_idx  = (int*)  alloc(BKQ*4);
  float* t_mask = (float*)alloc(BKQ*4);
  float* t_col  = (float*)alloc(BKQ*4);
  float* t_row  = (float*)alloc(BKQ*4);
  u16*   wtokT  = (u16*)  alloc((size_t)DD*CE*2);
  u16*   ctx_bf = (u16*)  alloc((size_t)BB*TOK*DD*2);
  u16*   ctxT_bf= (u16*)  alloc((size_t)BB*TOK*DD*2);
  u16*   ATb    = (u16*)  alloc((size_t)8192*DD*2);
  u16*   WVOb   = (u16*)  alloc((size_t)DD*8192*2);
  u16*   w1T    = (u16*)  alloc((size_t)LL*DD*MM*2);
  u16*   w2T    = (u16*)  alloc((size_t)LL*MM*DD*2);
  u16*   headsT = (u16*)  alloc((size_t)4*DD*DD*2);
  u16*   pw2T   = (u16*)  alloc((size_t)1024*DD*2);
  float* x      = (float*)alloc((size_t)BKQ*DD*4);
  u16*   x_bf   = (u16*)  alloc((size_t)BKQ*DD*2);
  u16*   z_bf   = (u16*)  alloc((size_t)BKQ*HH*DD*2);
  u16*   logits = (u16*)  alloc((size_t)BB*QH*TOK*2);
  u16*   att_bf = (u16*)  alloc((size_t)BB*QH*TOK*2);
  u16*   parts  = (u16*)  alloc((size_t)BB*8*QH*DD*2);
  u16*   c_flat = (u16*)  alloc((size_t)BKQ*8192*2);
  u16*   mid_bf = (u16*)  alloc((size_t)BKQ*MM*2);
  float* h4     = (float*)alloc((size_t)BKQ*2048*4);
  u16*   hp_bf  = (u16*)  alloc((size_t)BKQ*DD*2);
  float* hb4    = (float*)alloc(2048*4);
  float* cvec2  = (float*)alloc(1024*4);
  float* rot6d  = (float*)alloc((size_t)BKQ*NROT*4);
  if (off > ws_size) return;

  // job table for unified weight transposer
  PJobs J;
  int ntl = 0, nj = 0;
  auto addjob = [&](const float* s, u16* d, int R, int C){
    J.s[nj] = s; J.d[nj] = d; J.R[nj] = R; J.C[nj] = C; J.t0[nj] = ntl;
    ntl += ((R+31)/32) * ((C+31)/32);
    nj++;
  };
  addjob(Wtok, wtokT, CE, DD);
  for (int l = 0; l < LL; l++) addjob(W1 + (size_t)l*DD*MM, w1T + (size_t)l*MM*DD, DD, MM);
  for (int l = 0; l < LL; l++) addjob(W2 + (size_t)l*MM*DD, w2T + (size_t)l*DD*MM, MM, DD);
  addjob(offW1, headsT,            DD, DD);
  addjob(dW1,   headsT + DD*DD,    DD, DD);
  addjob(sW1,   headsT + 2*DD*DD,  DD, DD);
  addjob(pW1,   headsT + 3*DD*DD,  DD, DD);
  addjob(pW2,   pw2T, DD, NROT);
  J.t0[nj] = ntl; J.njobs = nj; J.ntiles = ntl;

  k_nms_topk<<<BB, 256, 0, stream>>>(scores, t_idx, t_mask, t_col, t_row);
  k_prep_all<<<2048, 256, 0, stream>>>(J, pW1, pb1, ibp, hb4, offb1, db1, sb1, pb2, cvec2);
  k_gemm_emb<<<dim3(DD/128, (BB*TOK)/128, 1), 256, 0, stream>>>(feat, wtokT, ctx_bf, ctxT_bf, btok, pos_emb);
  k_gather2<<<BKQ, 256, 0, stream>>>(ctx_bf, t_idx, x);

  for (int l = 0; l < LL; l++){
    // AT = scale * Wq·Wk^T and WVO = Wv·Wo (per-head) in one dispatch
    k_wqkvo<<<2048, 256, 0, stream>>>(Wq + (size_t)l*DD*DD, Wk + (size_t)l*DD*DD,
                                      Wv + (size_t)l*DD*DD, Wo + (size_t)l*DD*DD, ATb, WVOb);
    // z = LN1(x) @ AT^T  (z layout [b][q*16+h][dout])
    k_mf64<0,0,0,1,0,0,1><<<dim3(128,1), 256, 0, stream>>>(
        nullptr, x, g1 + l*DD, b1n + l*DD, ATb, nullptr,
        nullptr, z_bf, nullptr, 8192, DD, DD, DD, 1.f);
    // logits[b] = Z_b (256x512) @ ctx_b^T -> bf16
    k_gemm_bt64<1><<<dim3(TOK/64, 2, BB), 256, 0, stream>>>(
        z_bf, ctx_bf, nullptr, logits,
        DD, DD, DD, TOK, (long)QH*DD, (long)TOK*DD, (long)QH*TOK, 1);
    k_softmax<<<BB*QH, 256, 0, stream>>>(logits, att_bf);
    // parts[b*8+ks] = att_b @ ctxT_b^T over K-slice ks (bf16 partials)
    k_gemm_bt64<2><<<dim3(DD/64, 2, BB*8), 256, 0, stream>>>(
        att_bf, ctxT_bf, nullptr, parts,
        TOK/8, TOK, TOK, DD, (long)QH*TOK, (long)DD*TOK, (long)QH*DD, 8);
    k_red8<<<512, 256, 0, stream>>>(parts, c_flat);
    // x += c_flat @ WVO^T   (K=8192, ksplit=16, atomic)
    k_mf64<0,1,0,0,0,0,0><<<dim3(8,16), 256, 0, stream>>>(
        c_flat, nullptr, nullptr, nullptr, WVOb, nullptr,
        x, nullptr, nullptr, DD, 8192, 512, DD, 1.f);
    // mid = gelu(LN2(x) @ W1 + bf1)  -> bf16
    k_mf64<2,0,1,1,0,0,0><<<dim3(MM/64,1), 256, 0, stream>>>(
        nullptr, x, g2 + l*DD, b2n + l*DD, w1T + (size_t)l*DD*MM, bf1 + l*MM,
        nullptr, mid_bf, nullptr, MM, DD, DD, MM, 1.f);
    // x += mid @ W2 + bf2  (ksplit=8, atomic)
    k_mf64<0,1,0,0,0,0,0><<<dim3(8,8), 256, 0, stream>>>(
        mid_bf, nullptr, nullptr, nullptr, w2T + (size_t)l*MM*DD, bf2 + l*DD,
        x, nullptr, nullptr, DD, MM, MM/8, DD, 1.f);
  }

  // heads: h4 = relu(x @ [offW1|dW1|sW1|pW1] + hb4), with bf16 copy of the pose slice
  k_cvt_bf16<<<32, 256, 0, stream>>>(x, x_bf, BKQ*DD/4);
  k_mf64<1,0,0,0,0,1,0><<<dim3(32,1), 256, 0, stream>>>(
      x_bf, nullptr, nullptr, nullptr, headsT, hb4,
      h4, nullptr, hp_bf, 2048, DD, DD, 2048, 1.f);
  // rot6d = h_p @ pW2 + (pb2 + ibp)
  k_mf64<0,0,0,0,1,0,0><<<dim3(16,1), 256, 0, stream>>>(
      hp_bf, nullptr, nullptr, nullptr, pw2T, cvec2,
      rot6d, nullptr, nullptr, NROT, DD, DD, NROT, 1.f);
  k_final<<<BKQ, 256, 0, stream>>>(h4, rot6d, offW2, offb2, dW2, db2, sW2, sb2,
                                   K_cam, useful, t_mask, t_col, t_row, out);
}